// Round 5
// baseline (300.021 us; speedup 1.0000x reference)
//
#include <hip/hip_runtime.h>
#include <cmath>
#include <type_traits>

#define HEADS 4
#define FDIM 128   // H*D == IN_DIM == 128
#define NEG 0.2f
#define NBUCK 8    // src-locality buckets per dst segment
#define NSEG 64    // bins per dst segment: bucket(3b) * xcd(3b)
#define EPT 16     // edges per thread in hist
#define XCC_GETREG 63508   // hwreg(HW_REG_XCC_ID=20, offset 0, size 32)

typedef __attribute__((ext_vector_type(8))) __bf16 bf16x8;
typedef __attribute__((ext_vector_type(8))) _Float16 h16x8;
typedef __attribute__((ext_vector_type(4))) float f32x4;

// ---------------------------------------------------------------------------
// Unified W preprocessing + counts/aux zeroing, one dispatch.
// ---------------------------------------------------------------------------
__global__ __launch_bounds__(256) void prep_kernel(
    const float* __restrict__ W1, const float* __restrict__ al1,
    const float* __restrict__ ar1,
    const float* __restrict__ W2, const float* __restrict__ al2,
    const float* __restrict__ ar2,
    __bf16* __restrict__ wf1, __bf16* __restrict__ wext1,
    _Float16* __restrict__ wf2, _Float16* __restrict__ wext2,
    int* __restrict__ counts, int nb, int* __restrict__ aux, int naux)
{
    const int b = blockIdx.x, tid = threadIdx.x;
    if (b < 256) {
        int idx = (b & 127) * 256 + tid;        // < 32768
        int j = idx & 7;
        int r = idx >> 3;
        int c = r & 15; r >>= 4;
        int t = r & 7;  r >>= 3;
        int kq = r & 15;
        int hl = r >> 4;
        if (b < 128) {
            float v = W1[(t * 16 + c) * 128 + kq * 8 + j];
            __bf16 hi = (__bf16)v;
            wf1[idx] = (hl == 0) ? hi : (__bf16)(v - (float)hi);
        } else {
            float v = W2[(t * 16 + c) * 128 + kq * 8 + j];
            _Float16 hi = (_Float16)v;
            wf2[idx] = (hl == 0) ? hi : (_Float16)(v - (float)hi);
        }
    } else if (b < 258) {
        const float* W  = (b == 256) ? W1 : W2;
        const float* al = (b == 256) ? al1 : al2;
        const float* ar = (b == 256) ? ar1 : ar2;
        __shared__ float val[1024];
        #pragma unroll
        for (int ch = 0; ch < 4; ++ch) {
            int idx = ch * 256 + tid;           // < 1024
            int c = idx >> 7, k = idx & 127;
            int h = c & 3;
            const float* a = (c < 4) ? al : ar;
            float s = 0.f;
            for (int d = 0; d < 32; ++d)
                s += a[h * 32 + d] * W[(h * 32 + d) * 128 + k];
            val[c * 128 + k] = s;
        }
        __syncthreads();
        #pragma unroll
        for (int ch = 0; ch < 16; ++ch) {
            int idx = tid * 16 + ch;            // < 4096
            int j = idx & 7;
            int r = idx >> 3;
            int c = r & 15; r >>= 4;
            int kq = r & 15;
            int hl = r >> 4;
            float v = (c < 8) ? val[c * 128 + kq * 8 + j] : 0.f;
            if (b == 256) {
                __bf16 hi = (__bf16)v;
                wext1[idx] = (hl == 0) ? hi : (__bf16)(v - (float)hi);
            } else {
                _Float16 hi = (_Float16)v;
                wext2[idx] = (hl == 0) ? hi : (_Float16)(v - (float)hi);
            }
        }
    } else {
        if (b == 258) {
            for (int k = tid; k < naux; k += 256) aux[k] = 0;
        }
        int i0 = ((b - 258) * 256 + tid) * 4;
        if (i0 + 3 < nb) {
            *(int4*)&counts[i0] = make_int4(0, 0, 0, 0);
        } else {
            for (int i = i0; i < nb; ++i) counts[i] = 0;
        }
    }
}

// ---------------------------------------------------------------------------
// MFMA GEMM body, fp32-X path (layer 1): bf16 hi/lo 3-term.
// ---------------------------------------------------------------------------
__device__ __forceinline__ void gemm_body_f32(
    const float* __restrict__ X, const bf16x8* __restrict__ wf,
    const bf16x8* __restrict__ wext, _Float16* __restrict__ featH,
    float* __restrict__ el, float* __restrict__ er,
    int nnodes, int tile0, int tend, int stride, bf16x8* lw)
{
    const int tid = threadIdx.x;
    const int wave = tid >> 6, lane = tid & 63;
    const int l15 = lane & 15, quad = lane >> 4;

    int tile = tile0;
    float xr[32], xn[32];

    auto loadX = [&](int tl, float* dst) {
        int nodeA = tl * 64 + wave * 16 + l15;
        bool v = nodeA < nnodes;
        const float4* xp = (const float4*)(X + (size_t)nodeA * 128);
        #pragma unroll
        for (int ks = 0; ks < 4; ++ks) {
            float4 a = v ? xp[ks * 8 + quad * 2]     : make_float4(0.f, 0.f, 0.f, 0.f);
            float4 b = v ? xp[ks * 8 + quad * 2 + 1] : make_float4(0.f, 0.f, 0.f, 0.f);
            dst[ks * 8 + 0] = a.x; dst[ks * 8 + 1] = a.y;
            dst[ks * 8 + 2] = a.z; dst[ks * 8 + 3] = a.w;
            dst[ks * 8 + 4] = b.x; dst[ks * 8 + 5] = b.y;
            dst[ks * 8 + 6] = b.z; dst[ks * 8 + 7] = b.w;
        }
    };

    loadX(tile, xr);                      // issue X loads first
    for (int i = tid; i < 2048; i += 256) lw[i] = wf[i];
    __syncthreads();

    while (true) {
        int next = tile + stride;
        if (next < tend) loadX(next, xn);

        f32x4 acc[9];
        #pragma unroll
        for (int t = 0; t < 9; ++t) acc[t] = (f32x4){0.f, 0.f, 0.f, 0.f};

        #pragma unroll
        for (int ks = 0; ks < 4; ++ks) {
            bf16x8 ahi, alo;
            #pragma unroll
            for (int j = 0; j < 8; ++j) {
                float xv = xr[ks * 8 + j];
                __bf16 h = (__bf16)xv;
                ahi[j] = h;
                alo[j] = (__bf16)(xv - (float)h);
            }
            const int kq = ks * 4 + quad;

            {
                bf16x8 bh = wext[(kq) * 16 + l15];
                bf16x8 bl = wext[(16 + kq) * 16 + l15];
                acc[8] = __builtin_amdgcn_mfma_f32_16x16x32_bf16(ahi, bh, acc[8], 0, 0, 0);
                acc[8] = __builtin_amdgcn_mfma_f32_16x16x32_bf16(alo, bh, acc[8], 0, 0, 0);
                acc[8] = __builtin_amdgcn_mfma_f32_16x16x32_bf16(ahi, bl, acc[8], 0, 0, 0);
            }
            #pragma unroll
            for (int t = 0; t < 8; ++t) {
                bf16x8 bh = lw[(kq * 8 + t) * 16 + l15];
                bf16x8 bl = wf[2048 + (kq * 8 + t) * 16 + l15];   // lo from global
                acc[t] = __builtin_amdgcn_mfma_f32_16x16x32_bf16(ahi, bh, acc[t], 0, 0, 0);
                acc[t] = __builtin_amdgcn_mfma_f32_16x16x32_bf16(alo, bh, acc[t], 0, 0, 0);
                acc[t] = __builtin_amdgcn_mfma_f32_16x16x32_bf16(ahi, bl, acc[t], 0, 0, 0);
            }
        }

        const int nodeC = tile * 64 + wave * 16 + quad * 4;
        #pragma unroll
        for (int r = 0; r < 4; ++r) {
            int gn = nodeC + r;
            if (gn < nnodes) {
                #pragma unroll
                for (int t = 0; t < 8; ++t)
                    featH[(size_t)gn * 128 + t * 16 + l15] = (_Float16)acc[t][r];
            }
        }
        if (l15 < 8) {
            #pragma unroll
            for (int r = 0; r < 4; ++r) {
                int gn = nodeC + r;
                if (gn < nnodes) {
                    if (l15 < 4) el[gn * HEADS + l15] = acc[8][r];
                    else         er[gn * HEADS + (l15 - 4)] = acc[8][r];
                }
            }
        }

        if (next >= tend) break;
        #pragma unroll
        for (int i = 0; i < 32; ++i) xr[i] = xn[i];
        tile = next;
    }
}

// ---------------------------------------------------------------------------
// MFMA GEMM body, fp16-X path (layer 2): X exact fp16, W fp16 hi/lo, 2-term.
// ---------------------------------------------------------------------------
__device__ __forceinline__ void gemm_body_f16(
    const _Float16* __restrict__ X, const h16x8* __restrict__ wf,
    const h16x8* __restrict__ wext, _Float16* __restrict__ featH,
    float* __restrict__ el, float* __restrict__ er,
    int nnodes, int tile0, int tend, int stride, h16x8* lw)
{
    const int tid = threadIdx.x;
    const int wave = tid >> 6, lane = tid & 63;
    const int l15 = lane & 15, quad = lane >> 4;

    int tile = tile0;
    h16x8 xr[4], xn[4];

    auto loadX = [&](int tl, h16x8* dst) {
        int nodeA = tl * 64 + wave * 16 + l15;
        bool v = nodeA < nnodes;
        const h16x8* xp = (const h16x8*)(X + (size_t)nodeA * 128);
        #pragma unroll
        for (int ks = 0; ks < 4; ++ks) {
            if (v) {
                dst[ks] = xp[ks * 4 + quad];
            } else {
                #pragma unroll
                for (int j = 0; j < 8; ++j) dst[ks][j] = (_Float16)0.f;
            }
        }
    };

    loadX(tile, xr);
    for (int i = tid; i < 2048; i += 256) lw[i] = wf[i];
    __syncthreads();

    while (true) {
        int next = tile + stride;
        if (next < tend) loadX(next, xn);

        f32x4 acc[9];
        #pragma unroll
        for (int t = 0; t < 9; ++t) acc[t] = (f32x4){0.f, 0.f, 0.f, 0.f};

        #pragma unroll
        for (int ks = 0; ks < 4; ++ks) {
            h16x8 a = xr[ks];
            const int kq = ks * 4 + quad;
            {
                h16x8 bh = wext[(kq) * 16 + l15];
                h16x8 bl = wext[(16 + kq) * 16 + l15];
                acc[8] = __builtin_amdgcn_mfma_f32_16x16x32_f16(a, bh, acc[8], 0, 0, 0);
                acc[8] = __builtin_amdgcn_mfma_f32_16x16x32_f16(a, bl, acc[8], 0, 0, 0);
            }
            #pragma unroll
            for (int t = 0; t < 8; ++t) {
                h16x8 bh = lw[(kq * 8 + t) * 16 + l15];
                h16x8 bl = wf[2048 + (kq * 8 + t) * 16 + l15];   // lo from global
                acc[t] = __builtin_amdgcn_mfma_f32_16x16x32_f16(a, bh, acc[t], 0, 0, 0);
                acc[t] = __builtin_amdgcn_mfma_f32_16x16x32_f16(a, bl, acc[t], 0, 0, 0);
            }
        }

        const int nodeC = tile * 64 + wave * 16 + quad * 4;
        #pragma unroll
        for (int r = 0; r < 4; ++r) {
            int gn = nodeC + r;
            if (gn < nnodes) {
                #pragma unroll
                for (int t = 0; t < 8; ++t)
                    featH[(size_t)gn * 128 + t * 16 + l15] = (_Float16)acc[t][r];
            }
        }
        if (l15 < 8) {
            #pragma unroll
            for (int r = 0; r < 4; ++r) {
                int gn = nodeC + r;
                if (gn < nnodes) {
                    if (l15 < 4) el[gn * HEADS + l15] = acc[8][r];
                    else         er[gn * HEADS + (l15 - 4)] = acc[8][r];
                }
            }
        }

        if (next >= tend) break;
        #pragma unroll
        for (int i = 0; i < 4; ++i) xr[i] = xn[i];
        tile = next;
    }
}

// ---------------------------------------------------------------------------
// hist: per-XCD. Counts go to bin = dst*64 + bucket*8 + xcd via WORKGROUP-
// scope atomics (execute in the local XCD L2 - no cross-XCD line bouncing,
// no memory-side RMW). Edge is appended to this XCD's queue so that scatter
// can route the same edge to the same XCD regardless of block placement.
// ---------------------------------------------------------------------------
__device__ __forceinline__ void hist_body(
    const int* __restrict__ src, const int* __restrict__ dst,
    int* __restrict__ counts, int2* __restrict__ queue, int* __restrict__ qtail,
    int qcap, int nedges, int shift, int b, int x)
{
    int i0 = (b * 256 + threadIdx.x) * EPT;
    int2* qx = queue + (size_t)x * qcap;
    if (i0 + EPT - 1 < nedges) {
        int s[EPT], d[EPT];
        #pragma unroll
        for (int q = 0; q < EPT / 4; ++q) {
            *(int4*)&s[q * 4] = *(const int4*)&src[i0 + q * 4];
            *(int4*)&d[q * 4] = *(const int4*)&dst[i0 + q * 4];
        }
        int base = __hip_atomic_fetch_add(&qtail[x], EPT, __ATOMIC_RELAXED,
                                          __HIP_MEMORY_SCOPE_WORKGROUP);
        #pragma unroll
        for (int q = 0; q < EPT; ++q)
            qx[base + q] = make_int2(s[q], d[q]);
        #pragma unroll
        for (int q = 0; q < EPT; ++q)
            (void)__hip_atomic_fetch_add(
                &counts[(d[q] << 6) + ((s[q] >> shift) << 3) + x], 1,
                __ATOMIC_RELAXED, __HIP_MEMORY_SCOPE_WORKGROUP);
    } else if (i0 < nedges) {
        int cnt = nedges - i0;                  // < EPT here
        int base = __hip_atomic_fetch_add(&qtail[x], cnt, __ATOMIC_RELAXED,
                                          __HIP_MEMORY_SCOPE_WORKGROUP);
        for (int k = 0; k < cnt; ++k) {
            int s = src[i0 + k], d = dst[i0 + k];
            qx[base + k] = make_int2(s, d);
            (void)__hip_atomic_fetch_add(
                &counts[(d << 6) + ((s >> shift) << 3) + x], 1,
                __ATOMIC_RELAXED, __HIP_MEMORY_SCOPE_WORKGROUP);
        }
    }
}

// ---------------------------------------------------------------------------
// scatter: each wave work-steals 1024-edge chunks from ITS OWN XCD's queue
// (claim cursor = local atomic), bumps the per-(bin,xcd) cursor (local
// atomic-return) and writes the csr slot. Zero device-scope atomics.
// ---------------------------------------------------------------------------
__device__ __forceinline__ void scatter_body(
    const int2* __restrict__ queue, const int* __restrict__ qtail,
    int* __restrict__ claim, int* __restrict__ cursor,
    int* __restrict__ csr_src, int qcap, int shift, int x)
{
    const int lane = threadIdx.x & 63;
    const int nq = qtail[x];
    const int2* qx = queue + (size_t)x * qcap;
    while (true) {
        int c = 0;
        if (lane == 0)
            c = __hip_atomic_fetch_add(&claim[x], 1, __ATOMIC_RELAXED,
                                       __HIP_MEMORY_SCOPE_WORKGROUP);
        c = __builtin_amdgcn_readfirstlane(c);
        const int start = c * 1024;
        if (start >= nq) break;
        const int i0 = start + lane * 16;
        if (i0 + 15 < nq) {
            const int4* qp = (const int4*)(qx + i0);
            int4 e[8];
            #pragma unroll
            for (int j = 0; j < 8; ++j) e[j] = qp[j];
            #pragma unroll
            for (int j = 0; j < 8; ++j) {
                int bin0 = (e[j].y << 6) + ((e[j].x >> shift) << 3) + x;
                int bin1 = (e[j].w << 6) + ((e[j].z >> shift) << 3) + x;
                int p0 = __hip_atomic_fetch_add(&cursor[bin0], 1, __ATOMIC_RELAXED,
                                                __HIP_MEMORY_SCOPE_WORKGROUP);
                int p1 = __hip_atomic_fetch_add(&cursor[bin1], 1, __ATOMIC_RELAXED,
                                                __HIP_MEMORY_SCOPE_WORKGROUP);
                csr_src[p0] = e[j].x;
                csr_src[p1] = e[j].z;
            }
        } else {
            for (int i = i0; i < nq && i < i0 + 16; ++i) {
                int2 e = qx[i];
                int bin = (e.y << 6) + ((e.x >> shift) << 3) + x;
                int p = __hip_atomic_fetch_add(&cursor[bin], 1, __ATOMIC_RELAXED,
                                               __HIP_MEMORY_SCOPE_WORKGROUP);
                csr_src[p] = e.x;
            }
        }
    }
}

// ---------------------------------------------------------------------------
// Fused dispatches. Edge blocks get LOW block ids.
// ---------------------------------------------------------------------------
__global__ __launch_bounds__(256) void fused_gemm_hist(
    const float* __restrict__ X, const bf16x8* __restrict__ wf,
    const bf16x8* __restrict__ wext, _Float16* __restrict__ featH,
    float* __restrict__ el, float* __restrict__ er, int nnodes,
    int t0, int tend, int gemm_blocks, int edge_blocks,
    const int* __restrict__ src, const int* __restrict__ dst,
    int* __restrict__ counts, int2* __restrict__ queue,
    int* __restrict__ qtail, int qcap, int nedges, int shift)
{
    __shared__ bf16x8 lw[2048];
    if ((int)blockIdx.x >= edge_blocks)
        gemm_body_f32(X, wf, wext, featH, el, er, nnodes,
                      t0 + (blockIdx.x - edge_blocks), tend, gemm_blocks, lw);
    else {
        int x = (int)(__builtin_amdgcn_s_getreg(XCC_GETREG) & 7u);
        hist_body(src, dst, counts, queue, qtail, qcap, nedges, shift,
                  blockIdx.x, x);
    }
}

__global__ __launch_bounds__(256) void fused_gemm_scatter(
    const float* __restrict__ X, const bf16x8* __restrict__ wf,
    const bf16x8* __restrict__ wext, _Float16* __restrict__ featH,
    float* __restrict__ el, float* __restrict__ er, int nnodes,
    int t0, int tend, int gemm_blocks, int edge_blocks,
    const int2* __restrict__ queue, const int* __restrict__ qtail,
    int* __restrict__ claim, int* __restrict__ cursor,
    int* __restrict__ csr_src, int qcap, int shift)
{
    __shared__ bf16x8 lw[2048];
    if ((int)blockIdx.x >= edge_blocks)
        gemm_body_f32(X, wf, wext, featH, el, er, nnodes,
                      t0 + (blockIdx.x - edge_blocks), tend, gemm_blocks, lw);
    else {
        int x = (int)(__builtin_amdgcn_s_getreg(XCC_GETREG) & 7u);
        scatter_body(queue, qtail, claim, cursor, csr_src, qcap, shift, x);
    }
}

// standalone GEMM (layer 2, fp16 input, fp16 W 2-term)
__global__ __launch_bounds__(256) void gemm_mfma_f16_kernel(
    const _Float16* __restrict__ X, const h16x8* __restrict__ wf,
    const h16x8* __restrict__ wext, _Float16* __restrict__ featH,
    float* __restrict__ el, float* __restrict__ er, int nnodes, int ntiles)
{
    __shared__ h16x8 lw[2048];
    gemm_body_f16(X, wf, wext, featH, el, er, nnodes,
                  blockIdx.x, ntiles, gridDim.x, lw);
}

// ---------------------------------------------------------------------------
// Two-dispatch scan over NB_T = N*64 bins. scan23 writes offsets + cursor.
// ---------------------------------------------------------------------------
__global__ __launch_bounds__(256) void scan1_kernel(
    const int* __restrict__ counts, int* __restrict__ offsets,
    int* __restrict__ bsums, int n)
{
    __shared__ int wsums[4];
    const int tid = threadIdx.x, lane = tid & 63, w = tid >> 6;
    const int i = blockIdx.x * 1024 + tid * 4;

    int4 v = make_int4(0, 0, 0, 0);
    if (i + 3 < n) v = *(const int4*)&counts[i];
    else {
        if (i < n)     v.x = counts[i];
        if (i + 1 < n) v.y = counts[i + 1];
        if (i + 2 < n) v.z = counts[i + 2];
    }
    int s0 = v.x, s1 = s0 + v.y, s2 = s1 + v.z, s3 = s2 + v.w;

    int x = s3;
    #pragma unroll
    for (int off = 1; off < 64; off <<= 1) {
        int t = __shfl_up(x, off, 64);
        if (lane >= off) x += t;
    }
    if (lane == 63) wsums[w] = x;
    __syncthreads();
    int wbase = 0;
    #pragma unroll
    for (int k = 0; k < 4; ++k) if (k < w) wbase += wsums[k];

    int tbase = wbase + x - s3;
    if (i < n)     offsets[i]     = tbase;
    if (i + 1 < n) offsets[i + 1] = tbase + s0;
    if (i + 2 < n) offsets[i + 2] = tbase + s1;
    if (i + 3 < n) offsets[i + 3] = tbase + s2;
    if (tid == 255) bsums[blockIdx.x] = wbase + x;
}

__global__ __launch_bounds__(256) void scan23_kernel(
    int* __restrict__ offsets, int* __restrict__ cursor,
    const int* __restrict__ bsums, int n, int nedges)
{
    __shared__ int sbase;
    const int tid = threadIdx.x, b = blockIdx.x;
    if (tid < 64) {
        int s = 0;
        for (int i = tid; i < b; i += 64) s += bsums[i];
        #pragma unroll
        for (int off = 1; off < 64; off <<= 1) s += __shfl_xor(s, off, 64);
        if (tid == 0) sbase = s;
    }
    __syncthreads();
    const int base = sbase;
    const int i = b * 1024 + tid * 4;
    #pragma unroll
    for (int k = 0; k < 4; ++k)
        if (i + k < n) {
            int o = offsets[i + k] + base;
            offsets[i + k] = o;
            cursor[i + k] = o;
        }
    if (b == 0 && tid == 0) offsets[n] = nedges;
}

// ---------------------------------------------------------------------------
// Gather aggregation: one wave per node, 4 edges/iter, depth-2 pipeline.
// ---------------------------------------------------------------------------
template <bool MEAN>
__global__ __launch_bounds__(256) void aggregate_kernel(
    const _Float16* __restrict__ featH, const float* __restrict__ el,
    const float* __restrict__ er, const int* __restrict__ offsets,
    const int* __restrict__ csr_src, void* __restrict__ outp, int nnodes)
{
    const int n = (blockIdx.x * 256 + threadIdx.x) >> 6;   // wave-uniform
    if (n >= nnodes) return;
    const int lane = threadIdx.x & 63;
    const int g = lane >> 4, u = lane & 15, h = u >> 2;
    const int beg = offsets[n * NSEG], end = offsets[n * NSEG + NSEG];
    const float ern = er[n * HEADS + h];
    const int iters = (end - beg + 3) >> 2;

    float a[8];
    #pragma unroll
    for (int p = 0; p < 8; ++p) a[p] = 0.f;
    float sw = 0.f;

    const h16x8* __restrict__ frow = (const h16x8*)featH;

    int ja = beg + g;
    int jb = ja + 4;
    bool va = ja < end, vb = jb < end;
    int sa = va ? csr_src[ja] : 0;
    int sb = vb ? csr_src[jb] : 0;
    float qa = el[sa * HEADS + h];
    float qb = el[sb * HEADS + h];
    h16x8 fa = frow[(size_t)sa * 16 + u];
    h16x8 fb = frow[(size_t)sb * 16 + u];

    for (int it = 0; it < iters; ++it) {
        int jc = ja + 8;
        bool vc = jc < end;
        int sc = vc ? csr_src[jc] : 0;
        float qc = el[sc * HEADS + h];
        h16x8 fc = frow[(size_t)sc * 16 + u];

        float e = qa + ern;
        e = e > 0.f ? e : NEG * e;
        float w2 = va ? __expf(e) : 0.f;
        #pragma unroll
        for (int p = 0; p < 8; ++p) a[p] += w2 * (float)fa[p];
        sw += w2;

        ja = jb; va = vb; sa = sb; qa = qb; fa = fb;
        jb = jc; vb = vc; sb = sc; qb = qc; fb = fc;
    }

    #pragma unroll
    for (int p = 0; p < 8; ++p) {
        a[p] += __shfl_xor(a[p], 16, 64);
        a[p] += __shfl_xor(a[p], 32, 64);
    }
    sw += __shfl_xor(sw, 16, 64);
    sw += __shfl_xor(sw, 32, 64);

    float inv = sw > 0.f ? 1.f / sw : 0.f;
    float r[8];
    #pragma unroll
    for (int p = 0; p < 8; ++p) {
        float t = a[p] * inv;
        r[p] = t > 0.f ? t : __expf(t) - 1.f;   // ELU
    }

    if (!MEAN) {
        if (g == 0) {
            h16x8 o;
            #pragma unroll
            for (int p = 0; p < 8; ++p) o[p] = (_Float16)r[p];
            ((h16x8*)outp)[(size_t)n * 16 + u] = o;
        }
    } else {
        #pragma unroll
        for (int p = 0; p < 8; ++p) {
            r[p] += __shfl_xor(r[p], 4, 64);
            r[p] += __shfl_xor(r[p], 8, 64);
        }
        if (g == 0 && u < 4) {
            float* out = (float*)outp;
            float4* o4 = (float4*)(out + (size_t)n * 32 + u * 8);
            o4[0] = make_float4(0.25f * r[0], 0.25f * r[1], 0.25f * r[2], 0.25f * r[3]);
            o4[1] = make_float4(0.25f * r[4], 0.25f * r[5], 0.25f * r[6], 0.25f * r[7]);
        }
    }
}

// ---------------------------------------------------------------------------
extern "C" void kernel_launch(void* const* d_in, const int* in_sizes, int n_in,
                              void* d_out, int out_size, void* d_ws, size_t ws_size,
                              hipStream_t stream)
{
    const float* x   = (const float*)d_in[0];
    const int*   src = (const int*)d_in[1];
    const int*   dst = (const int*)d_in[2];
    const float* W1  = (const float*)d_in[3];
    const float* al1 = (const float*)d_in[4];
    const float* ar1 = (const float*)d_in[5];
    const float* W2  = (const float*)d_in[6];
    const float* al2 = (const float*)d_in[7];
    const float* ar2 = (const float*)d_in[8];

    const int N = in_sizes[0] / FDIM;
    const int E = in_sizes[1];
    const int NB_T = N * NSEG;

    int shift = 0;
    while (((N - 1) >> shift) > (NBUCK - 1)) ++shift;

    _Float16* h1 = (_Float16*)d_ws;
    _Float16* featH = h1 + (size_t)N * FDIM;
    float* el = (float*)(featH + (size_t)N * FDIM);
    float* er = el + (size_t)N * HEADS;
    uintptr_t qp = ((uintptr_t)(er + (size_t)N * HEADS) + 15) & ~(uintptr_t)15;
    int2* queue  = (int2*)qp;                       // 8 queues x E entries
    int* counts  = (int*)(queue + (size_t)8 * E);
    int* offsets = counts + NB_T;
    int* cursor  = offsets + (NB_T + 1);
    int* csr_src = cursor + NB_T;
    int* bsums   = csr_src + E;                     // nscan sums (<=4096)
    int* qtail   = bsums + 4096;                    // 8
    int* claim   = qtail + 8;                       // 8
    uintptr_t wp = ((uintptr_t)(claim + 8) + 63) & ~(uintptr_t)63;
    __bf16* wf1     = (__bf16*)wp;                  // 32768 bf16
    __bf16* wext1   = wf1 + 32768;                  // 4096 bf16
    _Float16* wf2   = (_Float16*)(wext1 + 4096);    // 32768 fp16
    _Float16* wext2 = wf2 + 32768;                  // 4096 fp16

    const int ntiles = (N + 63) / 64;
    const int halfT  = (ntiles + 1) / 2;
    const int gA = halfT < 256 ? halfT : 256;
    const int gB = (ntiles - halfT) < 256 ? (ntiles - halfT) : 256;
    const int hist_grid = ((E + EPT - 1) / EPT + 255) / 256;
    const int scat_grid = 512;                      // work-stealing consumers
    const int agg_grid  = (N + 3) / 4;              // 1 wave/node
    const int nscan     = (NB_T + 1023) / 1024;     // <= 4096
    const int zblocks   = ((NB_T + 3) / 4 + 255) / 256;
    const int g2 = ntiles < 512 ? ntiles : 512;

    // ---- W preprocessing + counts/aux zeroing ----
    prep_kernel<<<258 + zblocks, 256, 0, stream>>>(
        W1, al1, ar1, W2, al2, ar2, wf1, wext1, wf2, wext2,
        counts, NB_T, bsums, 4096 + 16);

    // ---- [hist (XCD-local atomics, queue append) ∥ gemm1 first half] ----
    fused_gemm_hist<<<hist_grid + gA, 256, 0, stream>>>(
        x, (const bf16x8*)wf1, (const bf16x8*)wext1, featH, el, er, N,
        0, halfT, gA, hist_grid, src, dst, counts, queue, qtail, E, E, shift);

    // ---- two-dispatch scan (offsets + cursor) ----
    scan1_kernel<<<nscan, 256, 0, stream>>>(counts, offsets, bsums, NB_T);
    scan23_kernel<<<nscan, 256, 0, stream>>>(offsets, cursor, bsums, NB_T, E);

    // ---- [scatter (XCD-local work-steal) ∥ gemm1 second half] ----
    fused_gemm_scatter<<<scat_grid + gB, 256, 0, stream>>>(
        x, (const bf16x8*)wf1, (const bf16x8*)wext1, featH, el, er, N,
        halfT, ntiles, gB, scat_grid, queue, qtail, claim, cursor,
        csr_src, E, shift);

    // ---- layer 1 aggregate ----
    aggregate_kernel<false><<<agg_grid, 256, 0, stream>>>(
        featH, el, er, offsets, csr_src, (void*)h1, N);

    // ---- layer 2 ----
    gemm_mfma_f16_kernel<<<g2, 256, 0, stream>>>(
        h1, (const h16x8*)wf2, (const h16x8*)wext2, featH, el, er, N, ntiles);
    aggregate_kernel<true><<<agg_grid, 256, 0, stream>>>(
        featH, el, er, offsets, csr_src, d_out, N);
}

// Round 6
// 238.809 us; speedup vs baseline: 1.2563x; 1.2563x over previous
//
#include <hip/hip_runtime.h>
#include <cmath>
#include <type_traits>

#define HEADS 4
#define FDIM 128   // H*D == IN_DIM == 128
#define NEG 0.2f
#define NBUCK 8    // src-locality buckets per dst segment

typedef __attribute__((ext_vector_type(8))) __bf16 bf16x8;
typedef __attribute__((ext_vector_type(8))) _Float16 h16x8;
typedef __attribute__((ext_vector_type(4))) float f32x4;

// ---------------------------------------------------------------------------
// Unified W preprocessing + counts zeroing, one dispatch.
// W1 -> bf16 hi/lo (layer-1 fp32 X, 3-term). W2 -> fp16 hi/lo (layer-2 X is
// exact fp16, so X*Whi + X*Wlo is 2-term and ~22-bit accurate in W).
// ---------------------------------------------------------------------------
__global__ __launch_bounds__(256) void prep_kernel(
    const float* __restrict__ W1, const float* __restrict__ al1,
    const float* __restrict__ ar1,
    const float* __restrict__ W2, const float* __restrict__ al2,
    const float* __restrict__ ar2,
    __bf16* __restrict__ wf1, __bf16* __restrict__ wext1,
    _Float16* __restrict__ wf2, _Float16* __restrict__ wext2,
    int* __restrict__ counts, int nb)
{
    const int b = blockIdx.x, tid = threadIdx.x;
    if (b < 256) {
        int idx = (b & 127) * 256 + tid;        // < 32768
        int j = idx & 7;
        int r = idx >> 3;
        int c = r & 15; r >>= 4;
        int t = r & 7;  r >>= 3;
        int kq = r & 15;
        int hl = r >> 4;
        if (b < 128) {
            float v = W1[(t * 16 + c) * 128 + kq * 8 + j];
            __bf16 hi = (__bf16)v;
            wf1[idx] = (hl == 0) ? hi : (__bf16)(v - (float)hi);
        } else {
            float v = W2[(t * 16 + c) * 128 + kq * 8 + j];
            _Float16 hi = (_Float16)v;
            wf2[idx] = (hl == 0) ? hi : (_Float16)(v - (float)hi);
        }
    } else if (b < 258) {
        const float* W  = (b == 256) ? W1 : W2;
        const float* al = (b == 256) ? al1 : al2;
        const float* ar = (b == 256) ? ar1 : ar2;
        __shared__ float val[1024];
        #pragma unroll
        for (int ch = 0; ch < 4; ++ch) {
            int idx = ch * 256 + tid;           // < 1024
            int c = idx >> 7, k = idx & 127;
            int h = c & 3;
            const float* a = (c < 4) ? al : ar;
            float s = 0.f;
            for (int d = 0; d < 32; ++d)
                s += a[h * 32 + d] * W[(h * 32 + d) * 128 + k];
            val[c * 128 + k] = s;
        }
        __syncthreads();
        #pragma unroll
        for (int ch = 0; ch < 16; ++ch) {
            int idx = tid * 16 + ch;            // < 4096
            int j = idx & 7;
            int r = idx >> 3;
            int c = r & 15; r >>= 4;
            int kq = r & 15;
            int hl = r >> 4;
            float v = (c < 8) ? val[c * 128 + kq * 8 + j] : 0.f;
            if (b == 256) {
                __bf16 hi = (__bf16)v;
                wext1[idx] = (hl == 0) ? hi : (__bf16)(v - (float)hi);
            } else {
                _Float16 hi = (_Float16)v;
                wext2[idx] = (hl == 0) ? hi : (_Float16)(v - (float)hi);
            }
        }
    } else {
        int i0 = ((b - 258) * 256 + tid) * 4;
        if (i0 + 3 < nb) {
            *(int4*)&counts[i0] = make_int4(0, 0, 0, 0);
        } else {
            for (int i = i0; i < nb; ++i) counts[i] = 0;
        }
    }
}

// ---------------------------------------------------------------------------
// MFMA GEMM body, fp32-X path (layer 1): bf16 hi/lo 3-term.
// W-hi in LDS (32 KB), W-lo from global; X reg-prefetch.
// ---------------------------------------------------------------------------
__device__ __forceinline__ void gemm_body_f32(
    const float* __restrict__ X, const bf16x8* __restrict__ wf,
    const bf16x8* __restrict__ wext, _Float16* __restrict__ featH,
    float* __restrict__ el, float* __restrict__ er,
    int nnodes, int tile0, int tend, int stride, bf16x8* lw)
{
    const int tid = threadIdx.x;
    const int wave = tid >> 6, lane = tid & 63;
    const int l15 = lane & 15, quad = lane >> 4;

    int tile = tile0;
    float xr[32], xn[32];

    auto loadX = [&](int tl, float* dst) {
        int nodeA = tl * 64 + wave * 16 + l15;
        bool v = nodeA < nnodes;
        const float4* xp = (const float4*)(X + (size_t)nodeA * 128);
        #pragma unroll
        for (int ks = 0; ks < 4; ++ks) {
            float4 a = v ? xp[ks * 8 + quad * 2]     : make_float4(0.f, 0.f, 0.f, 0.f);
            float4 b = v ? xp[ks * 8 + quad * 2 + 1] : make_float4(0.f, 0.f, 0.f, 0.f);
            dst[ks * 8 + 0] = a.x; dst[ks * 8 + 1] = a.y;
            dst[ks * 8 + 2] = a.z; dst[ks * 8 + 3] = a.w;
            dst[ks * 8 + 4] = b.x; dst[ks * 8 + 5] = b.y;
            dst[ks * 8 + 6] = b.z; dst[ks * 8 + 7] = b.w;
        }
    };

    loadX(tile, xr);                      // issue X loads first
    for (int i = tid; i < 2048; i += 256) lw[i] = wf[i];
    __syncthreads();

    while (true) {
        int next = tile + stride;
        if (next < tend) loadX(next, xn);

        f32x4 acc[9];
        #pragma unroll
        for (int t = 0; t < 9; ++t) acc[t] = (f32x4){0.f, 0.f, 0.f, 0.f};

        #pragma unroll
        for (int ks = 0; ks < 4; ++ks) {
            bf16x8 ahi, alo;
            #pragma unroll
            for (int j = 0; j < 8; ++j) {
                float xv = xr[ks * 8 + j];
                __bf16 h = (__bf16)xv;
                ahi[j] = h;
                alo[j] = (__bf16)(xv - (float)h);
            }
            const int kq = ks * 4 + quad;

            {
                bf16x8 bh = wext[(kq) * 16 + l15];
                bf16x8 bl = wext[(16 + kq) * 16 + l15];
                acc[8] = __builtin_amdgcn_mfma_f32_16x16x32_bf16(ahi, bh, acc[8], 0, 0, 0);
                acc[8] = __builtin_amdgcn_mfma_f32_16x16x32_bf16(alo, bh, acc[8], 0, 0, 0);
                acc[8] = __builtin_amdgcn_mfma_f32_16x16x32_bf16(ahi, bl, acc[8], 0, 0, 0);
            }
            #pragma unroll
            for (int t = 0; t < 8; ++t) {
                bf16x8 bh = lw[(kq * 8 + t) * 16 + l15];
                bf16x8 bl = wf[2048 + (kq * 8 + t) * 16 + l15];   // lo from global
                acc[t] = __builtin_amdgcn_mfma_f32_16x16x32_bf16(ahi, bh, acc[t], 0, 0, 0);
                acc[t] = __builtin_amdgcn_mfma_f32_16x16x32_bf16(alo, bh, acc[t], 0, 0, 0);
                acc[t] = __builtin_amdgcn_mfma_f32_16x16x32_bf16(ahi, bl, acc[t], 0, 0, 0);
            }
        }

        const int nodeC = tile * 64 + wave * 16 + quad * 4;
        #pragma unroll
        for (int r = 0; r < 4; ++r) {
            int gn = nodeC + r;
            if (gn < nnodes) {
                #pragma unroll
                for (int t = 0; t < 8; ++t)
                    featH[(size_t)gn * 128 + t * 16 + l15] = (_Float16)acc[t][r];
            }
        }
        if (l15 < 8) {
            #pragma unroll
            for (int r = 0; r < 4; ++r) {
                int gn = nodeC + r;
                if (gn < nnodes) {
                    if (l15 < 4) el[gn * HEADS + l15] = acc[8][r];
                    else         er[gn * HEADS + (l15 - 4)] = acc[8][r];
                }
            }
        }

        if (next >= tend) break;
        #pragma unroll
        for (int i = 0; i < 32; ++i) xr[i] = xn[i];
        tile = next;
    }
}

// ---------------------------------------------------------------------------
// MFMA GEMM body, fp16-X path (layer 2): X exact fp16, W fp16 hi/lo, 2-term.
// 72 MFMA/tile vs 108, no per-element repack VALU.
// ---------------------------------------------------------------------------
__device__ __forceinline__ void gemm_body_f16(
    const _Float16* __restrict__ X, const h16x8* __restrict__ wf,
    const h16x8* __restrict__ wext, _Float16* __restrict__ featH,
    float* __restrict__ el, float* __restrict__ er,
    int nnodes, int tile0, int tend, int stride, h16x8* lw)
{
    const int tid = threadIdx.x;
    const int wave = tid >> 6, lane = tid & 63;
    const int l15 = lane & 15, quad = lane >> 4;

    int tile = tile0;
    h16x8 xr[4], xn[4];

    auto loadX = [&](int tl, h16x8* dst) {
        int nodeA = tl * 64 + wave * 16 + l15;
        bool v = nodeA < nnodes;
        const h16x8* xp = (const h16x8*)(X + (size_t)nodeA * 128);
        #pragma unroll
        for (int ks = 0; ks < 4; ++ks) {
            if (v) {
                dst[ks] = xp[ks * 4 + quad];
            } else {
                #pragma unroll
                for (int j = 0; j < 8; ++j) dst[ks][j] = (_Float16)0.f;
            }
        }
    };

    loadX(tile, xr);
    for (int i = tid; i < 2048; i += 256) lw[i] = wf[i];
    __syncthreads();

    while (true) {
        int next = tile + stride;
        if (next < tend) loadX(next, xn);

        f32x4 acc[9];
        #pragma unroll
        for (int t = 0; t < 9; ++t) acc[t] = (f32x4){0.f, 0.f, 0.f, 0.f};

        #pragma unroll
        for (int ks = 0; ks < 4; ++ks) {
            h16x8 a = xr[ks];
            const int kq = ks * 4 + quad;
            {
                h16x8 bh = wext[(kq) * 16 + l15];
                h16x8 bl = wext[(16 + kq) * 16 + l15];
                acc[8] = __builtin_amdgcn_mfma_f32_16x16x32_f16(a, bh, acc[8], 0, 0, 0);
                acc[8] = __builtin_amdgcn_mfma_f32_16x16x32_f16(a, bl, acc[8], 0, 0, 0);
            }
            #pragma unroll
            for (int t = 0; t < 8; ++t) {
                h16x8 bh = lw[(kq * 8 + t) * 16 + l15];
                h16x8 bl = wf[2048 + (kq * 8 + t) * 16 + l15];   // lo from global
                acc[t] = __builtin_amdgcn_mfma_f32_16x16x32_f16(a, bh, acc[t], 0, 0, 0);
                acc[t] = __builtin_amdgcn_mfma_f32_16x16x32_f16(a, bl, acc[t], 0, 0, 0);
            }
        }

        const int nodeC = tile * 64 + wave * 16 + quad * 4;
        #pragma unroll
        for (int r = 0; r < 4; ++r) {
            int gn = nodeC + r;
            if (gn < nnodes) {
                #pragma unroll
                for (int t = 0; t < 8; ++t)
                    featH[(size_t)gn * 128 + t * 16 + l15] = (_Float16)acc[t][r];
            }
        }
        if (l15 < 8) {
            #pragma unroll
            for (int r = 0; r < 4; ++r) {
                int gn = nodeC + r;
                if (gn < nnodes) {
                    if (l15 < 4) el[gn * HEADS + l15] = acc[8][r];
                    else         er[gn * HEADS + (l15 - 4)] = acc[8][r];
                }
            }
        }

        if (next >= tend) break;
        #pragma unroll
        for (int i = 0; i < 4; ++i) xr[i] = xn[i];
        tile = next;
    }
}

// ---------------------------------------------------------------------------
// hist / scatter bodies (R0-proven): 8 edges/thread, rank from atomic return.
// ---------------------------------------------------------------------------
__device__ __forceinline__ void hist_body(
    const int* __restrict__ src, const int* __restrict__ dst,
    int* __restrict__ counts, int* __restrict__ rank, int nedges, int shift, int b)
{
    int i0 = (b * 256 + threadIdx.x) * 8;
    if (i0 + 7 < nedges) {
        int4 d0 = *(const int4*)&dst[i0];
        int4 d1 = *(const int4*)&dst[i0 + 4];
        int4 s0 = *(const int4*)&src[i0];
        int4 s1 = *(const int4*)&src[i0 + 4];
        int4 r0, r1;
        r0.x = atomicAdd(&counts[d0.x * NBUCK + (s0.x >> shift)], 1);
        r0.y = atomicAdd(&counts[d0.y * NBUCK + (s0.y >> shift)], 1);
        r0.z = atomicAdd(&counts[d0.z * NBUCK + (s0.z >> shift)], 1);
        r0.w = atomicAdd(&counts[d0.w * NBUCK + (s0.w >> shift)], 1);
        r1.x = atomicAdd(&counts[d1.x * NBUCK + (s1.x >> shift)], 1);
        r1.y = atomicAdd(&counts[d1.y * NBUCK + (s1.y >> shift)], 1);
        r1.z = atomicAdd(&counts[d1.z * NBUCK + (s1.z >> shift)], 1);
        r1.w = atomicAdd(&counts[d1.w * NBUCK + (s1.w >> shift)], 1);
        *(int4*)&rank[i0]     = r0;
        *(int4*)&rank[i0 + 4] = r1;
    } else {
        for (int i = i0; i < nedges; ++i)
            rank[i] = atomicAdd(&counts[dst[i] * NBUCK + (src[i] >> shift)], 1);
    }
}

__device__ __forceinline__ void scatter_body(
    const int* __restrict__ src, const int* __restrict__ dst,
    const int* __restrict__ rank, const int* __restrict__ offsets,
    int* __restrict__ csr_src, int nedges, int shift, int b)
{
    int i0 = (b * 256 + threadIdx.x) * 8;
    if (i0 + 7 < nedges) {
        int4 d0 = *(const int4*)&dst[i0];
        int4 d1 = *(const int4*)&dst[i0 + 4];
        int4 r0 = *(const int4*)&rank[i0];
        int4 r1 = *(const int4*)&rank[i0 + 4];
        int4 s0 = *(const int4*)&src[i0];
        int4 s1 = *(const int4*)&src[i0 + 4];
        csr_src[offsets[d0.x * NBUCK + (s0.x >> shift)] + r0.x] = s0.x;
        csr_src[offsets[d0.y * NBUCK + (s0.y >> shift)] + r0.y] = s0.y;
        csr_src[offsets[d0.z * NBUCK + (s0.z >> shift)] + r0.z] = s0.z;
        csr_src[offsets[d0.w * NBUCK + (s0.w >> shift)] + r0.w] = s0.w;
        csr_src[offsets[d1.x * NBUCK + (s1.x >> shift)] + r1.x] = s1.x;
        csr_src[offsets[d1.y * NBUCK + (s1.y >> shift)] + r1.y] = s1.y;
        csr_src[offsets[d1.z * NBUCK + (s1.z >> shift)] + r1.z] = s1.z;
        csr_src[offsets[d1.w * NBUCK + (s1.w >> shift)] + r1.w] = s1.w;
    } else {
        for (int i = i0; i < nedges; ++i)
            csr_src[offsets[dst[i] * NBUCK + (src[i] >> shift)] + rank[i]] = src[i];
    }
}

// ---------------------------------------------------------------------------
// Fused dispatches (R0 ordering: gemm blocks first).
// ---------------------------------------------------------------------------
__global__ __launch_bounds__(256) void fused_gemm_hist(
    const float* __restrict__ X, const bf16x8* __restrict__ wf,
    const bf16x8* __restrict__ wext, _Float16* __restrict__ featH,
    float* __restrict__ el, float* __restrict__ er, int nnodes,
    int t0, int tend, int gemm_blocks,
    const int* __restrict__ src, const int* __restrict__ dst,
    int* __restrict__ counts, int* __restrict__ rank, int nedges, int shift)
{
    __shared__ bf16x8 lw[2048];
    if ((int)blockIdx.x < gemm_blocks)
        gemm_body_f32(X, wf, wext, featH, el, er, nnodes,
                      t0 + blockIdx.x, tend, gemm_blocks, lw);
    else
        hist_body(src, dst, counts, rank, nedges, shift, blockIdx.x - gemm_blocks);
}

__global__ __launch_bounds__(256) void fused_gemm_scatter(
    const float* __restrict__ X, const bf16x8* __restrict__ wf,
    const bf16x8* __restrict__ wext, _Float16* __restrict__ featH,
    float* __restrict__ el, float* __restrict__ er, int nnodes,
    int t0, int tend, int gemm_blocks,
    const int* __restrict__ src, const int* __restrict__ dst,
    const int* __restrict__ rank, const int* __restrict__ offsets,
    int* __restrict__ csr_src, int nedges, int shift)
{
    __shared__ bf16x8 lw[2048];
    if ((int)blockIdx.x < gemm_blocks)
        gemm_body_f32(X, wf, wext, featH, el, er, nnodes,
                      t0 + blockIdx.x, tend, gemm_blocks, lw);
    else
        scatter_body(src, dst, rank, offsets, csr_src, nedges, shift,
                     blockIdx.x - gemm_blocks);
}

// standalone GEMM (layer 2, fp16 input, fp16 W 2-term)
__global__ __launch_bounds__(256) void gemm_mfma_f16_kernel(
    const _Float16* __restrict__ X, const h16x8* __restrict__ wf,
    const h16x8* __restrict__ wext, _Float16* __restrict__ featH,
    float* __restrict__ el, float* __restrict__ er, int nnodes, int ntiles)
{
    __shared__ h16x8 lw[2048];
    gemm_body_f16(X, wf, wext, featH, el, er, nnodes,
                  blockIdx.x, ntiles, gridDim.x, lw);
}

// ---------------------------------------------------------------------------
// Two-dispatch scan (R0-proven).
// ---------------------------------------------------------------------------
__global__ __launch_bounds__(256) void scan1_kernel(
    const int* __restrict__ counts, int* __restrict__ offsets,
    int* __restrict__ bsums, int n)
{
    __shared__ int wsums[4];
    const int tid = threadIdx.x, lane = tid & 63, w = tid >> 6;
    const int i = blockIdx.x * 1024 + tid * 4;

    int4 v = make_int4(0, 0, 0, 0);
    if (i + 3 < n) v = *(const int4*)&counts[i];
    else {
        if (i < n)     v.x = counts[i];
        if (i + 1 < n) v.y = counts[i + 1];
        if (i + 2 < n) v.z = counts[i + 2];
    }
    int s0 = v.x, s1 = s0 + v.y, s2 = s1 + v.z, s3 = s2 + v.w;

    int x = s3;
    #pragma unroll
    for (int off = 1; off < 64; off <<= 1) {
        int t = __shfl_up(x, off, 64);
        if (lane >= off) x += t;
    }
    if (lane == 63) wsums[w] = x;
    __syncthreads();
    int wbase = 0;
    #pragma unroll
    for (int k = 0; k < 4; ++k) if (k < w) wbase += wsums[k];

    int tbase = wbase + x - s3;
    if (i < n)     offsets[i]     = tbase;
    if (i + 1 < n) offsets[i + 1] = tbase + s0;
    if (i + 2 < n) offsets[i + 2] = tbase + s1;
    if (i + 3 < n) offsets[i + 3] = tbase + s2;
    if (tid == 255) bsums[blockIdx.x] = wbase + x;
}

__global__ __launch_bounds__(256) void scan23_kernel(
    int* __restrict__ offsets, const int* __restrict__ bsums, int n, int nedges)
{
    __shared__ int sbase;
    const int tid = threadIdx.x, b = blockIdx.x;
    if (tid < 64) {
        int s = 0;
        for (int i = tid; i < b; i += 64) s += bsums[i];
        #pragma unroll
        for (int off = 1; off < 64; off <<= 1) s += __shfl_xor(s, off, 64);
        if (tid == 0) sbase = s;
    }
    __syncthreads();
    const int base = sbase;
    const int i = b * 1024 + tid * 4;
    #pragma unroll
    for (int k = 0; k < 4; ++k)
        if (i + k < n) offsets[i + k] += base;
    if (b == 0 && tid == 0) offsets[n] = nedges;
}

// ---------------------------------------------------------------------------
// Gather aggregation: one wave per node, 4 edges/iter, depth-2 pipeline.
// ---------------------------------------------------------------------------
template <bool MEAN>
__global__ __launch_bounds__(256) void aggregate_kernel(
    const _Float16* __restrict__ featH, const float* __restrict__ el,
    const float* __restrict__ er, const int* __restrict__ offsets,
    const int* __restrict__ csr_src, void* __restrict__ outp, int nnodes)
{
    const int n = (blockIdx.x * 256 + threadIdx.x) >> 6;   // wave-uniform
    if (n >= nnodes) return;
    const int lane = threadIdx.x & 63;
    const int g = lane >> 4, u = lane & 15, h = u >> 2;
    const int beg = offsets[n * NBUCK], end = offsets[n * NBUCK + NBUCK];
    const float ern = er[n * HEADS + h];
    const int iters = (end - beg + 3) >> 2;

    float a[8];
    #pragma unroll
    for (int p = 0; p < 8; ++p) a[p] = 0.f;
    float sw = 0.f;

    const h16x8* __restrict__ frow = (const h16x8*)featH;

    int ja = beg + g;
    int jb = ja + 4;
    bool va = ja < end, vb = jb < end;
    int sa = va ? csr_src[ja] : 0;
    int sb = vb ? csr_src[jb] : 0;
    float qa = el[sa * HEADS + h];
    float qb = el[sb * HEADS + h];
    h16x8 fa = frow[(size_t)sa * 16 + u];
    h16x8 fb = frow[(size_t)sb * 16 + u];

    for (int it = 0; it < iters; ++it) {
        int jc = ja + 8;
        bool vc = jc < end;
        int sc = vc ? csr_src[jc] : 0;
        float qc = el[sc * HEADS + h];
        h16x8 fc = frow[(size_t)sc * 16 + u];

        float e = qa + ern;
        e = e > 0.f ? e : NEG * e;
        float w2 = va ? __expf(e) : 0.f;
        #pragma unroll
        for (int p = 0; p < 8; ++p) a[p] += w2 * (float)fa[p];
        sw += w2;

        ja = jb; va = vb; sa = sb; qa = qb; fa = fb;
        jb = jc; vb = vc; sb = sc; qb = qc; fb = fc;
    }

    #pragma unroll
    for (int p = 0; p < 8; ++p) {
        a[p] += __shfl_xor(a[p], 16, 64);
        a[p] += __shfl_xor(a[p], 32, 64);
    }
    sw += __shfl_xor(sw, 16, 64);
    sw += __shfl_xor(sw, 32, 64);

    float inv = sw > 0.f ? 1.f / sw : 0.f;
    float r[8];
    #pragma unroll
    for (int p = 0; p < 8; ++p) {
        float t = a[p] * inv;
        r[p] = t > 0.f ? t : __expf(t) - 1.f;   // ELU
    }

    if (!MEAN) {
        if (g == 0) {
            h16x8 o;
            #pragma unroll
            for (int p = 0; p < 8; ++p) o[p] = (_Float16)r[p];
            ((h16x8*)outp)[(size_t)n * 16 + u] = o;
        }
    } else {
        #pragma unroll
        for (int p = 0; p < 8; ++p) {
            r[p] += __shfl_xor(r[p], 4, 64);
            r[p] += __shfl_xor(r[p], 8, 64);
        }
        if (g == 0 && u < 4) {
            float* out = (float*)outp;
            float4* o4 = (float4*)(out + (size_t)n * 32 + u * 8);
            o4[0] = make_float4(0.25f * r[0], 0.25f * r[1], 0.25f * r[2], 0.25f * r[3]);
            o4[1] = make_float4(0.25f * r[4], 0.25f * r[5], 0.25f * r[6], 0.25f * r[7]);
        }
    }
}

// ---------------------------------------------------------------------------
extern "C" void kernel_launch(void* const* d_in, const int* in_sizes, int n_in,
                              void* d_out, int out_size, void* d_ws, size_t ws_size,
                              hipStream_t stream)
{
    const float* x   = (const float*)d_in[0];
    const int*   src = (const int*)d_in[1];
    const int*   dst = (const int*)d_in[2];
    const float* W1  = (const float*)d_in[3];
    const float* al1 = (const float*)d_in[4];
    const float* ar1 = (const float*)d_in[5];
    const float* W2  = (const float*)d_in[6];
    const float* al2 = (const float*)d_in[7];
    const float* ar2 = (const float*)d_in[8];

    const int N = in_sizes[0] / FDIM;
    const int E = in_sizes[1];
    const int NB = N * NBUCK;

    int shift = 0;
    while (((N - 1) >> shift) > (NBUCK - 1)) ++shift;

    _Float16* h1 = (_Float16*)d_ws;
    _Float16* featH = h1 + (size_t)N * FDIM;
    float* el = (float*)(featH + (size_t)N * FDIM);
    float* er = el + (size_t)N * HEADS;
    int* counts  = (int*)(er + (size_t)N * HEADS);
    int* offsets = counts + NB;
    int* rank    = offsets + (NB + 1);
    int* csr_src = rank + E;
    int* bsums   = csr_src + E;
    uintptr_t wp = ((uintptr_t)(bsums + 512) + 63) & ~(uintptr_t)63;
    __bf16* wf1     = (__bf16*)wp;                 // 32768 bf16
    __bf16* wext1   = wf1 + 32768;                 // 4096 bf16
    _Float16* wf2   = (_Float16*)(wext1 + 4096);   // 32768 fp16
    _Float16* wext2 = wf2 + 32768;                 // 4096 fp16

    const int ntiles = (N + 63) / 64;
    const int halfT  = (ntiles + 1) / 2;
    const int gA = halfT < 256 ? halfT : 256;
    const int gB = (ntiles - halfT) < 256 ? (ntiles - halfT) : 256;
    const int edge8_grid = ((E + 7) / 8 + 255) / 256;
    const int agg_grid  = (N + 3) / 4;             // 1 wave/node, 4 waves/block
    const int nscan     = (NB + 1023) / 1024;
    const int zblocks   = ((NB + 3) / 4 + 255) / 256;
    const int g2 = ntiles < 512 ? ntiles : 512;

    // ---- W preprocessing + counts zeroing ----
    prep_kernel<<<258 + zblocks, 256, 0, stream>>>(
        W1, al1, ar1, W2, al2, ar2, wf1, wext1, wf2, wext2, counts, NB);

    // ---- [gemm1 first half ∥ hist] ----
    fused_gemm_hist<<<gA + edge8_grid, 256, 0, stream>>>(
        x, (const bf16x8*)wf1, (const bf16x8*)wext1, featH, el, er, N,
        0, halfT, gA, src, dst, counts, rank, E, shift);

    // ---- two-dispatch scan ----
    scan1_kernel<<<nscan, 256, 0, stream>>>(counts, offsets, bsums, NB);
    scan23_kernel<<<nscan, 256, 0, stream>>>(offsets, bsums, NB, E);

    // ---- [gemm1 second half ∥ scatter] ----
    fused_gemm_scatter<<<gB + edge8_grid, 256, 0, stream>>>(
        x, (const bf16x8*)wf1, (const bf16x8*)wext1, featH, el, er, N,
        halfT, ntiles, gB, src, dst, rank, offsets, csr_src, E, shift);

    // ---- layer 1 aggregate ----
    aggregate_kernel<false><<<agg_grid, 256, 0, stream>>>(
        featH, el, er, offsets, csr_src, (void*)h1, N);

    // ---- layer 2 ----
    gemm_mfma_f16_kernel<<<g2, 256, 0, stream>>>(
        h1, (const h16x8*)wf2, (const h16x8*)wext2, featH, el, er, N, ntiles);
    aggregate_kernel<true><<<agg_grid, 256, 0, stream>>>(
        featH, el, er, offsets, csr_src, d_out, N);
}

// Round 7
// 213.342 us; speedup vs baseline: 1.4063x; 1.1194x over previous
//
#include <hip/hip_runtime.h>
#include <cmath>
#include <type_traits>

#define HEADS 4
#define FDIM 128   // H*D == IN_DIM == 128
#define NEG 0.2f
#define NBUCK 8    // src-locality buckets per dst segment
#define CSHIFT 7   // coarse bucket = dst >> 7 (128 nodes/bucket)
#define CMASK 127

typedef __attribute__((ext_vector_type(8))) __bf16 bf16x8;
typedef __attribute__((ext_vector_type(8))) _Float16 h16x8;
typedef __attribute__((ext_vector_type(4))) float f32x4;

// ---------------------------------------------------------------------------
// W preprocessing only (no zeroing needed anymore: the radix count matrix is
// fully overwritten each run, LDS hists are zeroed in-kernel).
// ---------------------------------------------------------------------------
__global__ __launch_bounds__(256) void prep_kernel(
    const float* __restrict__ W1, const float* __restrict__ al1,
    const float* __restrict__ ar1,
    const float* __restrict__ W2, const float* __restrict__ al2,
    const float* __restrict__ ar2,
    __bf16* __restrict__ wf1, __bf16* __restrict__ wext1,
    _Float16* __restrict__ wf2, _Float16* __restrict__ wext2)
{
    const int b = blockIdx.x, tid = threadIdx.x;
    if (b < 256) {
        int idx = (b & 127) * 256 + tid;        // < 32768
        int j = idx & 7;
        int r = idx >> 3;
        int c = r & 15; r >>= 4;
        int t = r & 7;  r >>= 3;
        int kq = r & 15;
        int hl = r >> 4;
        if (b < 128) {
            float v = W1[(t * 16 + c) * 128 + kq * 8 + j];
            __bf16 hi = (__bf16)v;
            wf1[idx] = (hl == 0) ? hi : (__bf16)(v - (float)hi);
        } else {
            float v = W2[(t * 16 + c) * 128 + kq * 8 + j];
            _Float16 hi = (_Float16)v;
            wf2[idx] = (hl == 0) ? hi : (_Float16)(v - (float)hi);
        }
    } else {
        const float* W  = (b == 256) ? W1 : W2;
        const float* al = (b == 256) ? al1 : al2;
        const float* ar = (b == 256) ? ar1 : ar2;
        __shared__ float val[1024];
        #pragma unroll
        for (int ch = 0; ch < 4; ++ch) {
            int idx = ch * 256 + tid;           // < 1024
            int c = idx >> 7, k = idx & 127;
            int h = c & 3;
            const float* a = (c < 4) ? al : ar;
            float s = 0.f;
            for (int d = 0; d < 32; ++d)
                s += a[h * 32 + d] * W[(h * 32 + d) * 128 + k];
            val[c * 128 + k] = s;
        }
        __syncthreads();
        #pragma unroll
        for (int ch = 0; ch < 16; ++ch) {
            int idx = tid * 16 + ch;            // < 4096
            int j = idx & 7;
            int r = idx >> 3;
            int c = r & 15; r >>= 4;
            int kq = r & 15;
            int hl = r >> 4;
            float v = (c < 8) ? val[c * 128 + kq * 8 + j] : 0.f;
            if (b == 256) {
                __bf16 hi = (__bf16)v;
                wext1[idx] = (hl == 0) ? hi : (__bf16)(v - (float)hi);
            } else {
                _Float16 hi = (_Float16)v;
                wext2[idx] = (hl == 0) ? hi : (_Float16)(v - (float)hi);
            }
        }
    }
}

// ---------------------------------------------------------------------------
// MFMA GEMM body, fp32-X path (layer 1): bf16 hi/lo 3-term.
// ---------------------------------------------------------------------------
__device__ __forceinline__ void gemm_body_f32(
    const float* __restrict__ X, const bf16x8* __restrict__ wf,
    const bf16x8* __restrict__ wext, _Float16* __restrict__ featH,
    float* __restrict__ el, float* __restrict__ er,
    int nnodes, int tile0, int tend, int stride, bf16x8* lw)
{
    const int tid = threadIdx.x;
    const int wave = tid >> 6, lane = tid & 63;
    const int l15 = lane & 15, quad = lane >> 4;

    int tile = tile0;
    float xr[32], xn[32];

    auto loadX = [&](int tl, float* dst) {
        int nodeA = tl * 64 + wave * 16 + l15;
        bool v = nodeA < nnodes;
        const float4* xp = (const float4*)(X + (size_t)nodeA * 128);
        #pragma unroll
        for (int ks = 0; ks < 4; ++ks) {
            float4 a = v ? xp[ks * 8 + quad * 2]     : make_float4(0.f, 0.f, 0.f, 0.f);
            float4 b = v ? xp[ks * 8 + quad * 2 + 1] : make_float4(0.f, 0.f, 0.f, 0.f);
            dst[ks * 8 + 0] = a.x; dst[ks * 8 + 1] = a.y;
            dst[ks * 8 + 2] = a.z; dst[ks * 8 + 3] = a.w;
            dst[ks * 8 + 4] = b.x; dst[ks * 8 + 5] = b.y;
            dst[ks * 8 + 6] = b.z; dst[ks * 8 + 7] = b.w;
        }
    };

    loadX(tile, xr);                      // issue X loads first
    for (int i = tid; i < 2048; i += 256) lw[i] = wf[i];
    __syncthreads();

    while (true) {
        int next = tile + stride;
        if (next < tend) loadX(next, xn);

        f32x4 acc[9];
        #pragma unroll
        for (int t = 0; t < 9; ++t) acc[t] = (f32x4){0.f, 0.f, 0.f, 0.f};

        #pragma unroll
        for (int ks = 0; ks < 4; ++ks) {
            bf16x8 ahi, alo;
            #pragma unroll
            for (int j = 0; j < 8; ++j) {
                float xv = xr[ks * 8 + j];
                __bf16 h = (__bf16)xv;
                ahi[j] = h;
                alo[j] = (__bf16)(xv - (float)h);
            }
            const int kq = ks * 4 + quad;

            {
                bf16x8 bh = wext[(kq) * 16 + l15];
                bf16x8 bl = wext[(16 + kq) * 16 + l15];
                acc[8] = __builtin_amdgcn_mfma_f32_16x16x32_bf16(ahi, bh, acc[8], 0, 0, 0);
                acc[8] = __builtin_amdgcn_mfma_f32_16x16x32_bf16(alo, bh, acc[8], 0, 0, 0);
                acc[8] = __builtin_amdgcn_mfma_f32_16x16x32_bf16(ahi, bl, acc[8], 0, 0, 0);
            }
            #pragma unroll
            for (int t = 0; t < 8; ++t) {
                bf16x8 bh = lw[(kq * 8 + t) * 16 + l15];
                bf16x8 bl = wf[2048 + (kq * 8 + t) * 16 + l15];   // lo from global
                acc[t] = __builtin_amdgcn_mfma_f32_16x16x32_bf16(ahi, bh, acc[t], 0, 0, 0);
                acc[t] = __builtin_amdgcn_mfma_f32_16x16x32_bf16(alo, bh, acc[t], 0, 0, 0);
                acc[t] = __builtin_amdgcn_mfma_f32_16x16x32_bf16(ahi, bl, acc[t], 0, 0, 0);
            }
        }

        const int nodeC = tile * 64 + wave * 16 + quad * 4;
        #pragma unroll
        for (int r = 0; r < 4; ++r) {
            int gn = nodeC + r;
            if (gn < nnodes) {
                #pragma unroll
                for (int t = 0; t < 8; ++t)
                    featH[(size_t)gn * 128 + t * 16 + l15] = (_Float16)acc[t][r];
            }
        }
        if (l15 < 8) {
            #pragma unroll
            for (int r = 0; r < 4; ++r) {
                int gn = nodeC + r;
                if (gn < nnodes) {
                    if (l15 < 4) el[gn * HEADS + l15] = acc[8][r];
                    else         er[gn * HEADS + (l15 - 4)] = acc[8][r];
                }
            }
        }

        if (next >= tend) break;
        #pragma unroll
        for (int i = 0; i < 32; ++i) xr[i] = xn[i];
        tile = next;
    }
}

// ---------------------------------------------------------------------------
// MFMA GEMM body, fp16-X path (layer 2): X exact fp16, W fp16 hi/lo, 2-term.
// ---------------------------------------------------------------------------
__device__ __forceinline__ void gemm_body_f16(
    const _Float16* __restrict__ X, const h16x8* __restrict__ wf,
    const h16x8* __restrict__ wext, _Float16* __restrict__ featH,
    float* __restrict__ el, float* __restrict__ er,
    int nnodes, int tile0, int tend, int stride, h16x8* lw)
{
    const int tid = threadIdx.x;
    const int wave = tid >> 6, lane = tid & 63;
    const int l15 = lane & 15, quad = lane >> 4;

    int tile = tile0;
    h16x8 xr[4], xn[4];

    auto loadX = [&](int tl, h16x8* dst) {
        int nodeA = tl * 64 + wave * 16 + l15;
        bool v = nodeA < nnodes;
        const h16x8* xp = (const h16x8*)(X + (size_t)nodeA * 128);
        #pragma unroll
        for (int ks = 0; ks < 4; ++ks) {
            if (v) {
                dst[ks] = xp[ks * 4 + quad];
            } else {
                #pragma unroll
                for (int j = 0; j < 8; ++j) dst[ks][j] = (_Float16)0.f;
            }
        }
    };

    loadX(tile, xr);
    for (int i = tid; i < 2048; i += 256) lw[i] = wf[i];
    __syncthreads();

    while (true) {
        int next = tile + stride;
        if (next < tend) loadX(next, xn);

        f32x4 acc[9];
        #pragma unroll
        for (int t = 0; t < 9; ++t) acc[t] = (f32x4){0.f, 0.f, 0.f, 0.f};

        #pragma unroll
        for (int ks = 0; ks < 4; ++ks) {
            h16x8 a = xr[ks];
            const int kq = ks * 4 + quad;
            {
                h16x8 bh = wext[(kq) * 16 + l15];
                h16x8 bl = wext[(16 + kq) * 16 + l15];
                acc[8] = __builtin_amdgcn_mfma_f32_16x16x32_f16(a, bh, acc[8], 0, 0, 0);
                acc[8] = __builtin_amdgcn_mfma_f32_16x16x32_f16(a, bl, acc[8], 0, 0, 0);
            }
            #pragma unroll
            for (int t = 0; t < 8; ++t) {
                h16x8 bh = lw[(kq * 8 + t) * 16 + l15];
                h16x8 bl = wf[2048 + (kq * 8 + t) * 16 + l15];   // lo from global
                acc[t] = __builtin_amdgcn_mfma_f32_16x16x32_f16(a, bh, acc[t], 0, 0, 0);
                acc[t] = __builtin_amdgcn_mfma_f32_16x16x32_f16(a, bl, acc[t], 0, 0, 0);
            }
        }

        const int nodeC = tile * 64 + wave * 16 + quad * 4;
        #pragma unroll
        for (int r = 0; r < 4; ++r) {
            int gn = nodeC + r;
            if (gn < nnodes) {
                #pragma unroll
                for (int t = 0; t < 8; ++t)
                    featH[(size_t)gn * 128 + t * 16 + l15] = (_Float16)acc[t][r];
            }
        }
        if (l15 < 8) {
            #pragma unroll
            for (int r = 0; r < 4; ++r) {
                int gn = nodeC + r;
                if (gn < nnodes) {
                    if (l15 < 4) el[gn * HEADS + l15] = acc[8][r];
                    else         er[gn * HEADS + (l15 - 4)] = acc[8][r];
                }
            }
        }

        if (next >= tend) break;
        #pragma unroll
        for (int i = 0; i < 4; ++i) xr[i] = xn[i];
        tile = next;
    }
}

// ---------------------------------------------------------------------------
// Coarse radix pass bodies: LDS histogram over dst>>CSHIFT buckets, ZERO
// global atomics. Block eb owns edges [eb*2048, eb*2048+2048).
// ---------------------------------------------------------------------------
__device__ __forceinline__ void coarse_hist_body(
    const int* __restrict__ dst, int* __restrict__ histmat,
    int nedges, int nblk, int nbkt, int eb, int* chist)
{
    const int tid = threadIdx.x;
    for (int i = tid; i < nbkt; i += 256) chist[i] = 0;
    __syncthreads();
    int i0 = eb * 2048 + tid * 8;
    if (i0 + 7 < nedges) {
        int4 d0 = *(const int4*)&dst[i0];
        int4 d1 = *(const int4*)&dst[i0 + 4];
        atomicAdd(&chist[d0.x >> CSHIFT], 1);
        atomicAdd(&chist[d0.y >> CSHIFT], 1);
        atomicAdd(&chist[d0.z >> CSHIFT], 1);
        atomicAdd(&chist[d0.w >> CSHIFT], 1);
        atomicAdd(&chist[d1.x >> CSHIFT], 1);
        atomicAdd(&chist[d1.y >> CSHIFT], 1);
        atomicAdd(&chist[d1.z >> CSHIFT], 1);
        atomicAdd(&chist[d1.w >> CSHIFT], 1);
    } else {
        for (int i = i0; i < nedges; ++i)
            atomicAdd(&chist[dst[i] >> CSHIFT], 1);
    }
    __syncthreads();
    for (int i = tid; i < nbkt; i += 256)
        histmat[i * nblk + eb] = chist[i];
}

__device__ __forceinline__ void coarse_scatter_body(
    const int* __restrict__ src, const int* __restrict__ dst,
    const int* __restrict__ histoff, int2* __restrict__ tmp,
    int nedges, int nblk, int nbkt, int eb, int* chist)
{
    const int tid = threadIdx.x;
    for (int i = tid; i < nbkt; i += 256) chist[i] = 0;
    __syncthreads();
    int i0 = eb * 2048 + tid * 8;
    if (i0 + 7 < nedges) {
        int s[8], d[8];
        *(int4*)&s[0] = *(const int4*)&src[i0];
        *(int4*)&s[4] = *(const int4*)&src[i0 + 4];
        *(int4*)&d[0] = *(const int4*)&dst[i0];
        *(int4*)&d[4] = *(const int4*)&dst[i0 + 4];
        #pragma unroll
        for (int q = 0; q < 8; ++q) {
            int bkt = d[q] >> CSHIFT;
            int r = atomicAdd(&chist[bkt], 1);                 // LDS rank
            int pos = histoff[bkt * nblk + eb] + r;
            tmp[pos] = make_int2(s[q], d[q]);
        }
    } else {
        for (int i = i0; i < nedges; ++i) {
            int s = src[i], d = dst[i];
            int bkt = d >> CSHIFT;
            int r = atomicAdd(&chist[bkt], 1);
            tmp[histoff[bkt * nblk + eb] + r] = make_int2(s, d);
        }
    }
}

// ---------------------------------------------------------------------------
// Fused dispatches (gemm blocks first, R0-proven ordering).
// ---------------------------------------------------------------------------
__global__ __launch_bounds__(256) void fused_gemm_chist(
    const float* __restrict__ X, const bf16x8* __restrict__ wf,
    const bf16x8* __restrict__ wext, _Float16* __restrict__ featH,
    float* __restrict__ el, float* __restrict__ er, int nnodes,
    int t0, int tend, int gemm_blocks,
    const int* __restrict__ dst, int* __restrict__ histmat,
    int nedges, int nblk, int nbkt)
{
    __shared__ bf16x8 lw[2048];
    __shared__ int chist[512];
    if ((int)blockIdx.x < gemm_blocks)
        gemm_body_f32(X, wf, wext, featH, el, er, nnodes,
                      t0 + blockIdx.x, tend, gemm_blocks, lw);
    else
        coarse_hist_body(dst, histmat, nedges, nblk, nbkt, chist ? (blockIdx.x - gemm_blocks) : 0, chist);
}

__global__ __launch_bounds__(256) void fused_gemm_cscatter(
    const float* __restrict__ X, const bf16x8* __restrict__ wf,
    const bf16x8* __restrict__ wext, _Float16* __restrict__ featH,
    float* __restrict__ el, float* __restrict__ er, int nnodes,
    int t0, int tend, int gemm_blocks,
    const int* __restrict__ src, const int* __restrict__ dst,
    const int* __restrict__ histoff, int2* __restrict__ tmp,
    int nedges, int nblk, int nbkt)
{
    __shared__ bf16x8 lw[2048];
    __shared__ int chist[512];
    if ((int)blockIdx.x < gemm_blocks)
        gemm_body_f32(X, wf, wext, featH, el, er, nnodes,
                      t0 + blockIdx.x, tend, gemm_blocks, lw);
    else
        coarse_scatter_body(src, dst, histoff, tmp, nedges, nblk, nbkt,
                            blockIdx.x - gemm_blocks, chist);
}

// ---------------------------------------------------------------------------
// Fine sort: one block per coarse bucket. Edges to LDS, 1024-bin LDS hist
// (fine bin = (dst&127)*8 + srcbucket), LDS scan, LDS-rank scatter.
// Global bin id = bucket*1024 + fb == dst*8 + sbkt, so offsets[] writes are
// contiguous per bucket. Zero global atomics.
// ---------------------------------------------------------------------------
__global__ __launch_bounds__(256) void fine_sort_kernel(
    const int2* __restrict__ tmp, const int* __restrict__ histoff,
    int* __restrict__ csr_src, int* __restrict__ offsets,
    int nblk, int nbkt, int nb, int nedges, int shift)
{
    __shared__ int2 eds[4096];
    __shared__ int fh[1024];
    __shared__ int wsums[4];
    const int b = blockIdx.x, tid = threadIdx.x;
    const int lane = tid & 63, w = tid >> 6;

    const int base = histoff[b * nblk];
    const int endb = histoff[(b + 1) * nblk];    // histoff[nbkt*nblk] = E sentinel
    int cnt = endb - base;
    if (cnt > 4096) cnt = 4096;                  // Poisson max ~2.3k; safety clamp

    #pragma unroll
    for (int i = 0; i < 4; ++i) fh[tid + i * 256] = 0;
    __syncthreads();

    for (int i = tid; i < cnt; i += 256) {
        int2 e = tmp[base + i];
        eds[i] = e;
        int fb = ((e.y & CMASK) << 3) + (e.x >> shift);
        atomicAdd(&fh[fb], 1);
    }
    __syncthreads();

    // exclusive scan of fh[0..1024)
    int v0 = fh[tid * 4], v1 = fh[tid * 4 + 1], v2 = fh[tid * 4 + 2], v3 = fh[tid * 4 + 3];
    int s0 = v0, s1 = s0 + v1, s2 = s1 + v2, s3 = s2 + v3;
    int x = s3;
    #pragma unroll
    for (int off = 1; off < 64; off <<= 1) {
        int t = __shfl_up(x, off, 64);
        if (lane >= off) x += t;
    }
    if (lane == 63) wsums[w] = x;
    __syncthreads();
    int wbase = 0;
    #pragma unroll
    for (int k = 0; k < 4; ++k) if (k < w) wbase += wsums[k];
    const int tb = wbase + x - s3;

    // write scanned offsets back to fh (as scatter cursors) + global offsets
    int o0 = tb, o1 = tb + s0, o2 = tb + s1, o3 = tb + s2;
    fh[tid * 4]     = o0;
    fh[tid * 4 + 1] = o1;
    fh[tid * 4 + 2] = o2;
    fh[tid * 4 + 3] = o3;
    int g = b * 1024 + tid * 4;
    if (g < nb)     offsets[g]     = base + o0;
    if (g + 1 < nb) offsets[g + 1] = base + o1;
    if (g + 2 < nb) offsets[g + 2] = base + o2;
    if (g + 3 < nb) offsets[g + 3] = base + o3;
    __syncthreads();

    // scatter via LDS cursor bump
    for (int i = tid; i < cnt; i += 256) {
        int2 e = eds[i];
        int fb = ((e.y & CMASK) << 3) + (e.x >> shift);
        int p = atomicAdd(&fh[fb], 1);
        csr_src[base + p] = e.x;
    }
    if (b == 0 && tid == 0) offsets[nb] = nedges;
}

// standalone GEMM (layer 2, fp16 input, fp16 W 2-term)
__global__ __launch_bounds__(256) void gemm_mfma_f16_kernel(
    const _Float16* __restrict__ X, const h16x8* __restrict__ wf,
    const h16x8* __restrict__ wext, _Float16* __restrict__ featH,
    float* __restrict__ el, float* __restrict__ er, int nnodes, int ntiles)
{
    __shared__ h16x8 lw[2048];
    gemm_body_f16(X, wf, wext, featH, el, er, nnodes,
                  blockIdx.x, ntiles, gridDim.x, lw);
}

// ---------------------------------------------------------------------------
// Two-dispatch scan (proven), over the coarse count matrix.
// ---------------------------------------------------------------------------
__global__ __launch_bounds__(256) void scan1_kernel(
    const int* __restrict__ counts, int* __restrict__ offsets,
    int* __restrict__ bsums, int n)
{
    __shared__ int wsums[4];
    const int tid = threadIdx.x, lane = tid & 63, w = tid >> 6;
    const int i = blockIdx.x * 1024 + tid * 4;

    int4 v = make_int4(0, 0, 0, 0);
    if (i + 3 < n) v = *(const int4*)&counts[i];
    else {
        if (i < n)     v.x = counts[i];
        if (i + 1 < n) v.y = counts[i + 1];
        if (i + 2 < n) v.z = counts[i + 2];
    }
    int s0 = v.x, s1 = s0 + v.y, s2 = s1 + v.z, s3 = s2 + v.w;

    int x = s3;
    #pragma unroll
    for (int off = 1; off < 64; off <<= 1) {
        int t = __shfl_up(x, off, 64);
        if (lane >= off) x += t;
    }
    if (lane == 63) wsums[w] = x;
    __syncthreads();
    int wbase = 0;
    #pragma unroll
    for (int k = 0; k < 4; ++k) if (k < w) wbase += wsums[k];

    int tbase = wbase + x - s3;
    if (i < n)     offsets[i]     = tbase;
    if (i + 1 < n) offsets[i + 1] = tbase + s0;
    if (i + 2 < n) offsets[i + 2] = tbase + s1;
    if (i + 3 < n) offsets[i + 3] = tbase + s2;
    if (tid == 255) bsums[blockIdx.x] = wbase + x;
}

__global__ __launch_bounds__(256) void scan23_kernel(
    int* __restrict__ offsets, const int* __restrict__ bsums, int n, int nedges)
{
    __shared__ int sbase;
    const int tid = threadIdx.x, b = blockIdx.x;
    if (tid < 64) {
        int s = 0;
        for (int i = tid; i < b; i += 64) s += bsums[i];
        #pragma unroll
        for (int off = 1; off < 64; off <<= 1) s += __shfl_xor(s, off, 64);
        if (tid == 0) sbase = s;
    }
    __syncthreads();
    const int base = sbase;
    const int i = b * 1024 + tid * 4;
    #pragma unroll
    for (int k = 0; k < 4; ++k)
        if (i + k < n) offsets[i + k] += base;
    if (b == 0 && tid == 0) offsets[n] = nedges;
}

// ---------------------------------------------------------------------------
// Gather aggregation: one wave per node, 4 edges/iter, depth-2 pipeline.
// ---------------------------------------------------------------------------
template <bool MEAN>
__global__ __launch_bounds__(256) void aggregate_kernel(
    const _Float16* __restrict__ featH, const float* __restrict__ el,
    const float* __restrict__ er, const int* __restrict__ offsets,
    const int* __restrict__ csr_src, void* __restrict__ outp, int nnodes)
{
    const int n = (blockIdx.x * 256 + threadIdx.x) >> 6;   // wave-uniform
    if (n >= nnodes) return;
    const int lane = threadIdx.x & 63;
    const int g = lane >> 4, u = lane & 15, h = u >> 2;
    const int beg = offsets[n * NBUCK], end = offsets[n * NBUCK + NBUCK];
    const float ern = er[n * HEADS + h];
    const int iters = (end - beg + 3) >> 2;

    float a[8];
    #pragma unroll
    for (int p = 0; p < 8; ++p) a[p] = 0.f;
    float sw = 0.f;

    const h16x8* __restrict__ frow = (const h16x8*)featH;

    int ja = beg + g;
    int jb = ja + 4;
    bool va = ja < end, vb = jb < end;
    int sa = va ? csr_src[ja] : 0;
    int sb = vb ? csr_src[jb] : 0;
    float qa = el[sa * HEADS + h];
    float qb = el[sb * HEADS + h];
    h16x8 fa = frow[(size_t)sa * 16 + u];
    h16x8 fb = frow[(size_t)sb * 16 + u];

    for (int it = 0; it < iters; ++it) {
        int jc = ja + 8;
        bool vc = jc < end;
        int sc = vc ? csr_src[jc] : 0;
        float qc = el[sc * HEADS + h];
        h16x8 fc = frow[(size_t)sc * 16 + u];

        float e = qa + ern;
        e = e > 0.f ? e : NEG * e;
        float w2 = va ? __expf(e) : 0.f;
        #pragma unroll
        for (int p = 0; p < 8; ++p) a[p] += w2 * (float)fa[p];
        sw += w2;

        ja = jb; va = vb; sa = sb; qa = qb; fa = fb;
        jb = jc; vb = vc; sb = sc; qb = qc; fb = fc;
    }

    #pragma unroll
    for (int p = 0; p < 8; ++p) {
        a[p] += __shfl_xor(a[p], 16, 64);
        a[p] += __shfl_xor(a[p], 32, 64);
    }
    sw += __shfl_xor(sw, 16, 64);
    sw += __shfl_xor(sw, 32, 64);

    float inv = sw > 0.f ? 1.f / sw : 0.f;
    float r[8];
    #pragma unroll
    for (int p = 0; p < 8; ++p) {
        float t = a[p] * inv;
        r[p] = t > 0.f ? t : __expf(t) - 1.f;   // ELU
    }

    if (!MEAN) {
        if (g == 0) {
            h16x8 o;
            #pragma unroll
            for (int p = 0; p < 8; ++p) o[p] = (_Float16)r[p];
            ((h16x8*)outp)[(size_t)n * 16 + u] = o;
        }
    } else {
        #pragma unroll
        for (int p = 0; p < 8; ++p) {
            r[p] += __shfl_xor(r[p], 4, 64);
            r[p] += __shfl_xor(r[p], 8, 64);
        }
        if (g == 0 && u < 4) {
            float* out = (float*)outp;
            float4* o4 = (float4*)(out + (size_t)n * 32 + u * 8);
            o4[0] = make_float4(0.25f * r[0], 0.25f * r[1], 0.25f * r[2], 0.25f * r[3]);
            o4[1] = make_float4(0.25f * r[4], 0.25f * r[5], 0.25f * r[6], 0.25f * r[7]);
        }
    }
}

// ---------------------------------------------------------------------------
extern "C" void kernel_launch(void* const* d_in, const int* in_sizes, int n_in,
                              void* d_out, int out_size, void* d_ws, size_t ws_size,
                              hipStream_t stream)
{
    const float* x   = (const float*)d_in[0];
    const int*   src = (const int*)d_in[1];
    const int*   dst = (const int*)d_in[2];
    const float* W1  = (const float*)d_in[3];
    const float* al1 = (const float*)d_in[4];
    const float* ar1 = (const float*)d_in[5];
    const float* W2  = (const float*)d_in[6];
    const float* al2 = (const float*)d_in[7];
    const float* ar2 = (const float*)d_in[8];

    const int N = in_sizes[0] / FDIM;
    const int E = in_sizes[1];
    const int NB = N * NBUCK;

    int shift = 0;
    while (((N - 1) >> shift) > (NBUCK - 1)) ++shift;

    const int NBKT  = (N + CMASK) >> CSHIFT;       // coarse buckets (391)
    const int NBLK1 = (E + 2047) >> 11;            // edge blocks (391)
    const int n1    = NBKT * NBLK1;                // count-matrix entries

    _Float16* h1 = (_Float16*)d_ws;
    _Float16* featH = h1 + (size_t)N * FDIM;
    float* el = (float*)(featH + (size_t)N * FDIM);
    float* er = el + (size_t)N * HEADS;
    uintptr_t tp = ((uintptr_t)(er + (size_t)N * HEADS) + 15) & ~(uintptr_t)15;
    int2* tmp    = (int2*)tp;                      // E
    int* histmat = (int*)(tmp + E);                // n1
    int* histoff = histmat + n1;                   // n1 + 1
    int* offsets = histoff + (n1 + 1);             // NB + 1
    int* csr_src = offsets + (NB + 1);             // E
    int* bsums   = csr_src + E;                    // 512
    uintptr_t wp = ((uintptr_t)(bsums + 512) + 63) & ~(uintptr_t)63;
    __bf16* wf1     = (__bf16*)wp;                 // 32768 bf16
    __bf16* wext1   = wf1 + 32768;                 // 4096 bf16
    _Float16* wf2   = (_Float16*)(wext1 + 4096);   // 32768 fp16
    _Float16* wext2 = wf2 + 32768;                 // 4096 fp16

    const int ntiles = (N + 63) / 64;
    const int halfT  = (ntiles + 1) / 2;
    const int gA = halfT < 256 ? halfT : 256;
    const int gB = (ntiles - halfT) < 256 ? (ntiles - halfT) : 256;
    const int agg_grid  = (N + 3) / 4;             // 1 wave/node, 4 waves/block
    const int nscan     = (n1 + 1023) / 1024;      // <= 512 (bsums bound)
    const int g2 = ntiles < 512 ? ntiles : 512;

    // ---- W preprocessing (no zeroing needed) ----
    prep_kernel<<<258, 256, 0, stream>>>(
        W1, al1, ar1, W2, al2, ar2, wf1, wext1, wf2, wext2);

    // ---- [gemm1 first half ∥ coarse LDS hist] ----
    fused_gemm_chist<<<gA + NBLK1, 256, 0, stream>>>(
        x, (const bf16x8*)wf1, (const bf16x8*)wext1, featH, el, er, N,
        0, halfT, gA, dst, histmat, E, NBLK1, NBKT);

    // ---- scan of (bucket, block) count matrix ----
    scan1_kernel<<<nscan, 256, 0, stream>>>(histmat, histoff, bsums, n1);
    scan23_kernel<<<nscan, 256, 0, stream>>>(histoff, bsums, n1, E);

    // ---- [gemm1 second half ∥ coarse scatter (LDS ranks)] ----
    fused_gemm_cscatter<<<gB + NBLK1, 256, 0, stream>>>(
        x, (const bf16x8*)wf1, (const bf16x8*)wext1, featH, el, er, N,
        halfT, ntiles, gB, src, dst, histoff, tmp, E, NBLK1, NBKT);

    // ---- fine sort within buckets (LDS-only) ----
    fine_sort_kernel<<<NBKT, 256, 0, stream>>>(
        tmp, histoff, csr_src, offsets, NBLK1, NBKT, NB, E, shift);

    // ---- layer 1 aggregate ----
    aggregate_kernel<false><<<agg_grid, 256, 0, stream>>>(
        featH, el, er, offsets, csr_src, (void*)h1, N);

    // ---- layer 2 ----
    gemm_mfma_f16_kernel<<<g2, 256, 0, stream>>>(
        h1, (const h16x8*)wf2, (const h16x8*)wext2, featH, el, er, N, ntiles);
    aggregate_kernel<true><<<agg_grid, 256, 0, stream>>>(
        featH, el, er, offsets, csr_src, d_out, N);
}

// Round 8
// 210.822 us; speedup vs baseline: 1.4231x; 1.0120x over previous
//
#include <hip/hip_runtime.h>
#include <cmath>
#include <type_traits>

#define HEADS 4
#define FDIM 128   // H*D == IN_DIM == 128
#define NEG 0.2f
#define NBUCK 8    // src-locality buckets per dst segment
#define CSHIFT 7   // coarse bucket = dst >> 7 (128 nodes/bucket)
#define CMASK 127

typedef __attribute__((ext_vector_type(8))) __bf16 bf16x8;
typedef __attribute__((ext_vector_type(8))) _Float16 h16x8;
typedef __attribute__((ext_vector_type(4))) float f32x4;

// ---------------------------------------------------------------------------
// W preprocessing only.
// ---------------------------------------------------------------------------
__global__ __launch_bounds__(256) void prep_kernel(
    const float* __restrict__ W1, const float* __restrict__ al1,
    const float* __restrict__ ar1,
    const float* __restrict__ W2, const float* __restrict__ al2,
    const float* __restrict__ ar2,
    __bf16* __restrict__ wf1, __bf16* __restrict__ wext1,
    _Float16* __restrict__ wf2, _Float16* __restrict__ wext2)
{
    const int b = blockIdx.x, tid = threadIdx.x;
    if (b < 256) {
        int idx = (b & 127) * 256 + tid;        // < 32768
        int j = idx & 7;
        int r = idx >> 3;
        int c = r & 15; r >>= 4;
        int t = r & 7;  r >>= 3;
        int kq = r & 15;
        int hl = r >> 4;
        if (b < 128) {
            float v = W1[(t * 16 + c) * 128 + kq * 8 + j];
            __bf16 hi = (__bf16)v;
            wf1[idx] = (hl == 0) ? hi : (__bf16)(v - (float)hi);
        } else {
            float v = W2[(t * 16 + c) * 128 + kq * 8 + j];
            _Float16 hi = (_Float16)v;
            wf2[idx] = (hl == 0) ? hi : (_Float16)(v - (float)hi);
        }
    } else {
        const float* W  = (b == 256) ? W1 : W2;
        const float* al = (b == 256) ? al1 : al2;
        const float* ar = (b == 256) ? ar1 : ar2;
        __shared__ float val[1024];
        #pragma unroll
        for (int ch = 0; ch < 4; ++ch) {
            int idx = ch * 256 + tid;           // < 1024
            int c = idx >> 7, k = idx & 127;
            int h = c & 3;
            const float* a = (c < 4) ? al : ar;
            float s = 0.f;
            for (int d = 0; d < 32; ++d)
                s += a[h * 32 + d] * W[(h * 32 + d) * 128 + k];
            val[c * 128 + k] = s;
        }
        __syncthreads();
        #pragma unroll
        for (int ch = 0; ch < 16; ++ch) {
            int idx = tid * 16 + ch;            // < 4096
            int j = idx & 7;
            int r = idx >> 3;
            int c = r & 15; r >>= 4;
            int kq = r & 15;
            int hl = r >> 4;
            float v = (c < 8) ? val[c * 128 + kq * 8 + j] : 0.f;
            if (b == 256) {
                __bf16 hi = (__bf16)v;
                wext1[idx] = (hl == 0) ? hi : (__bf16)(v - (float)hi);
            } else {
                _Float16 hi = (_Float16)v;
                wext2[idx] = (hl == 0) ? hi : (_Float16)(v - (float)hi);
            }
        }
    }
}

// ---------------------------------------------------------------------------
// MFMA GEMM body, fp32-X path (layer 1): bf16 hi/lo 3-term.
// ---------------------------------------------------------------------------
__device__ __forceinline__ void gemm_body_f32(
    const float* __restrict__ X, const bf16x8* __restrict__ wf,
    const bf16x8* __restrict__ wext, _Float16* __restrict__ featH,
    float* __restrict__ el, float* __restrict__ er,
    int nnodes, int tile0, int tend, int stride, bf16x8* lw)
{
    const int tid = threadIdx.x;
    const int wave = tid >> 6, lane = tid & 63;
    const int l15 = lane & 15, quad = lane >> 4;

    int tile = tile0;
    float xr[32], xn[32];

    auto loadX = [&](int tl, float* dst) {
        int nodeA = tl * 64 + wave * 16 + l15;
        bool v = nodeA < nnodes;
        const float4* xp = (const float4*)(X + (size_t)nodeA * 128);
        #pragma unroll
        for (int ks = 0; ks < 4; ++ks) {
            float4 a = v ? xp[ks * 8 + quad * 2]     : make_float4(0.f, 0.f, 0.f, 0.f);
            float4 b = v ? xp[ks * 8 + quad * 2 + 1] : make_float4(0.f, 0.f, 0.f, 0.f);
            dst[ks * 8 + 0] = a.x; dst[ks * 8 + 1] = a.y;
            dst[ks * 8 + 2] = a.z; dst[ks * 8 + 3] = a.w;
            dst[ks * 8 + 4] = b.x; dst[ks * 8 + 5] = b.y;
            dst[ks * 8 + 6] = b.z; dst[ks * 8 + 7] = b.w;
        }
    };

    loadX(tile, xr);                      // issue X loads first
    for (int i = tid; i < 2048; i += 256) lw[i] = wf[i];
    __syncthreads();

    while (true) {
        int next = tile + stride;
        if (next < tend) loadX(next, xn);

        f32x4 acc[9];
        #pragma unroll
        for (int t = 0; t < 9; ++t) acc[t] = (f32x4){0.f, 0.f, 0.f, 0.f};

        #pragma unroll
        for (int ks = 0; ks < 4; ++ks) {
            bf16x8 ahi, alo;
            #pragma unroll
            for (int j = 0; j < 8; ++j) {
                float xv = xr[ks * 8 + j];
                __bf16 h = (__bf16)xv;
                ahi[j] = h;
                alo[j] = (__bf16)(xv - (float)h);
            }
            const int kq = ks * 4 + quad;

            {
                bf16x8 bh = wext[(kq) * 16 + l15];
                bf16x8 bl = wext[(16 + kq) * 16 + l15];
                acc[8] = __builtin_amdgcn_mfma_f32_16x16x32_bf16(ahi, bh, acc[8], 0, 0, 0);
                acc[8] = __builtin_amdgcn_mfma_f32_16x16x32_bf16(alo, bh, acc[8], 0, 0, 0);
                acc[8] = __builtin_amdgcn_mfma_f32_16x16x32_bf16(ahi, bl, acc[8], 0, 0, 0);
            }
            #pragma unroll
            for (int t = 0; t < 8; ++t) {
                bf16x8 bh = lw[(kq * 8 + t) * 16 + l15];
                bf16x8 bl = wf[2048 + (kq * 8 + t) * 16 + l15];   // lo from global
                acc[t] = __builtin_amdgcn_mfma_f32_16x16x32_bf16(ahi, bh, acc[t], 0, 0, 0);
                acc[t] = __builtin_amdgcn_mfma_f32_16x16x32_bf16(alo, bh, acc[t], 0, 0, 0);
                acc[t] = __builtin_amdgcn_mfma_f32_16x16x32_bf16(ahi, bl, acc[t], 0, 0, 0);
            }
        }

        const int nodeC = tile * 64 + wave * 16 + quad * 4;
        #pragma unroll
        for (int r = 0; r < 4; ++r) {
            int gn = nodeC + r;
            if (gn < nnodes) {
                #pragma unroll
                for (int t = 0; t < 8; ++t)
                    featH[(size_t)gn * 128 + t * 16 + l15] = (_Float16)acc[t][r];
            }
        }
        if (l15 < 8) {
            #pragma unroll
            for (int r = 0; r < 4; ++r) {
                int gn = nodeC + r;
                if (gn < nnodes) {
                    if (l15 < 4) el[gn * HEADS + l15] = acc[8][r];
                    else         er[gn * HEADS + (l15 - 4)] = acc[8][r];
                }
            }
        }

        if (next >= tend) break;
        #pragma unroll
        for (int i = 0; i < 32; ++i) xr[i] = xn[i];
        tile = next;
    }
}

// ---------------------------------------------------------------------------
// MFMA GEMM body, fp16-X path (layer 2): X exact fp16, W fp16 hi/lo, 2-term.
// ---------------------------------------------------------------------------
__device__ __forceinline__ void gemm_body_f16(
    const _Float16* __restrict__ X, const h16x8* __restrict__ wf,
    const h16x8* __restrict__ wext, _Float16* __restrict__ featH,
    float* __restrict__ el, float* __restrict__ er,
    int nnodes, int tile0, int tend, int stride, h16x8* lw)
{
    const int tid = threadIdx.x;
    const int wave = tid >> 6, lane = tid & 63;
    const int l15 = lane & 15, quad = lane >> 4;

    int tile = tile0;
    h16x8 xr[4], xn[4];

    auto loadX = [&](int tl, h16x8* dst) {
        int nodeA = tl * 64 + wave * 16 + l15;
        bool v = nodeA < nnodes;
        const h16x8* xp = (const h16x8*)(X + (size_t)nodeA * 128);
        #pragma unroll
        for (int ks = 0; ks < 4; ++ks) {
            if (v) {
                dst[ks] = xp[ks * 4 + quad];
            } else {
                #pragma unroll
                for (int j = 0; j < 8; ++j) dst[ks][j] = (_Float16)0.f;
            }
        }
    };

    loadX(tile, xr);
    for (int i = tid; i < 2048; i += 256) lw[i] = wf[i];
    __syncthreads();

    while (true) {
        int next = tile + stride;
        if (next < tend) loadX(next, xn);

        f32x4 acc[9];
        #pragma unroll
        for (int t = 0; t < 9; ++t) acc[t] = (f32x4){0.f, 0.f, 0.f, 0.f};

        #pragma unroll
        for (int ks = 0; ks < 4; ++ks) {
            h16x8 a = xr[ks];
            const int kq = ks * 4 + quad;
            {
                h16x8 bh = wext[(kq) * 16 + l15];
                h16x8 bl = wext[(16 + kq) * 16 + l15];
                acc[8] = __builtin_amdgcn_mfma_f32_16x16x32_f16(a, bh, acc[8], 0, 0, 0);
                acc[8] = __builtin_amdgcn_mfma_f32_16x16x32_f16(a, bl, acc[8], 0, 0, 0);
            }
            #pragma unroll
            for (int t = 0; t < 8; ++t) {
                h16x8 bh = lw[(kq * 8 + t) * 16 + l15];
                h16x8 bl = wf[2048 + (kq * 8 + t) * 16 + l15];   // lo from global
                acc[t] = __builtin_amdgcn_mfma_f32_16x16x32_f16(a, bh, acc[t], 0, 0, 0);
                acc[t] = __builtin_amdgcn_mfma_f32_16x16x32_f16(a, bl, acc[t], 0, 0, 0);
            }
        }

        const int nodeC = tile * 64 + wave * 16 + quad * 4;
        #pragma unroll
        for (int r = 0; r < 4; ++r) {
            int gn = nodeC + r;
            if (gn < nnodes) {
                #pragma unroll
                for (int t = 0; t < 8; ++t)
                    featH[(size_t)gn * 128 + t * 16 + l15] = (_Float16)acc[t][r];
            }
        }
        if (l15 < 8) {
            #pragma unroll
            for (int r = 0; r < 4; ++r) {
                int gn = nodeC + r;
                if (gn < nnodes) {
                    if (l15 < 4) el[gn * HEADS + l15] = acc[8][r];
                    else         er[gn * HEADS + (l15 - 4)] = acc[8][r];
                }
            }
        }

        if (next >= tend) break;
        #pragma unroll
        for (int i = 0; i < 4; ++i) xr[i] = xn[i];
        tile = next;
    }
}

// ---------------------------------------------------------------------------
// Coarse radix pass bodies: LDS histogram over dst>>CSHIFT buckets, ZERO
// global atomics. Block eb owns edges [eb*2048, eb*2048+2048).
// Edge payload is PACKED int32: (dst&127)<<16 | src (src < 2^16, N=50k).
// ---------------------------------------------------------------------------
__device__ __forceinline__ void coarse_hist_body(
    const int* __restrict__ dst, int* __restrict__ histmat,
    int nedges, int nblk, int nbkt, int eb, int* chist)
{
    const int tid = threadIdx.x;
    for (int i = tid; i < nbkt; i += 256) chist[i] = 0;
    __syncthreads();
    int i0 = eb * 2048 + tid * 8;
    if (i0 + 7 < nedges) {
        int4 d0 = *(const int4*)&dst[i0];
        int4 d1 = *(const int4*)&dst[i0 + 4];
        atomicAdd(&chist[d0.x >> CSHIFT], 1);
        atomicAdd(&chist[d0.y >> CSHIFT], 1);
        atomicAdd(&chist[d0.z >> CSHIFT], 1);
        atomicAdd(&chist[d0.w >> CSHIFT], 1);
        atomicAdd(&chist[d1.x >> CSHIFT], 1);
        atomicAdd(&chist[d1.y >> CSHIFT], 1);
        atomicAdd(&chist[d1.z >> CSHIFT], 1);
        atomicAdd(&chist[d1.w >> CSHIFT], 1);
    } else {
        for (int i = i0; i < nedges; ++i)
            atomicAdd(&chist[dst[i] >> CSHIFT], 1);
    }
    __syncthreads();
    for (int i = tid; i < nbkt; i += 256)
        histmat[i * nblk + eb] = chist[i];
}

__device__ __forceinline__ void coarse_scatter_body(
    const int* __restrict__ src, const int* __restrict__ dst,
    const int* __restrict__ histoff, int* __restrict__ tmp,
    int nedges, int nblk, int nbkt, int eb, int* chist)
{
    const int tid = threadIdx.x;
    for (int i = tid; i < nbkt; i += 256) chist[i] = 0;
    __syncthreads();
    int i0 = eb * 2048 + tid * 8;
    if (i0 + 7 < nedges) {
        int s[8], d[8];
        *(int4*)&s[0] = *(const int4*)&src[i0];
        *(int4*)&s[4] = *(const int4*)&src[i0 + 4];
        *(int4*)&d[0] = *(const int4*)&dst[i0];
        *(int4*)&d[4] = *(const int4*)&dst[i0 + 4];
        #pragma unroll
        for (int q = 0; q < 8; ++q) {
            int bkt = d[q] >> CSHIFT;
            int r = atomicAdd(&chist[bkt], 1);                 // LDS rank
            int pos = histoff[bkt * nblk + eb] + r;
            tmp[pos] = ((d[q] & CMASK) << 16) | s[q];
        }
    } else {
        for (int i = i0; i < nedges; ++i) {
            int s = src[i], d = dst[i];
            int bkt = d >> CSHIFT;
            int r = atomicAdd(&chist[bkt], 1);
            tmp[histoff[bkt * nblk + eb] + r] = ((d & CMASK) << 16) | s;
        }
    }
}

// ---------------------------------------------------------------------------
// Fused dispatches (gemm blocks first, proven ordering).
// ---------------------------------------------------------------------------
__global__ __launch_bounds__(256) void fused_gemm_chist(
    const float* __restrict__ X, const bf16x8* __restrict__ wf,
    const bf16x8* __restrict__ wext, _Float16* __restrict__ featH,
    float* __restrict__ el, float* __restrict__ er, int nnodes,
    int t0, int tend, int gemm_blocks,
    const int* __restrict__ dst, int* __restrict__ histmat,
    int nedges, int nblk, int nbkt)
{
    __shared__ bf16x8 lw[2048];
    __shared__ int chist[512];
    if ((int)blockIdx.x < gemm_blocks)
        gemm_body_f32(X, wf, wext, featH, el, er, nnodes,
                      t0 + blockIdx.x, tend, gemm_blocks, lw);
    else
        coarse_hist_body(dst, histmat, nedges, nblk, nbkt,
                         blockIdx.x - gemm_blocks, chist);
}

__global__ __launch_bounds__(256) void fused_gemm_cscatter(
    const float* __restrict__ X, const bf16x8* __restrict__ wf,
    const bf16x8* __restrict__ wext, _Float16* __restrict__ featH,
    float* __restrict__ el, float* __restrict__ er, int nnodes,
    int t0, int tend, int gemm_blocks,
    const int* __restrict__ src, const int* __restrict__ dst,
    const int* __restrict__ histoff, int* __restrict__ tmp,
    int nedges, int nblk, int nbkt)
{
    __shared__ bf16x8 lw[2048];
    __shared__ int chist[512];
    if ((int)blockIdx.x < gemm_blocks)
        gemm_body_f32(X, wf, wext, featH, el, er, nnodes,
                      t0 + blockIdx.x, tend, gemm_blocks, lw);
    else
        coarse_scatter_body(src, dst, histoff, tmp, nedges, nblk, nbkt,
                            blockIdx.x - gemm_blocks, chist);
}

// ---------------------------------------------------------------------------
// Fine sort: one block per coarse bucket. Packed edges to LDS (16 KB),
// 1024-bin LDS hist (fine bin = (dst&127)*8 + srcbucket), LDS scan,
// LDS-rank scatter. Zero global atomics.
// ---------------------------------------------------------------------------
__global__ __launch_bounds__(256) void fine_sort_kernel(
    const int* __restrict__ tmp, const int* __restrict__ histoff,
    int* __restrict__ csr_src, int* __restrict__ offsets,
    int nblk, int nbkt, int nb, int nedges, int shift)
{
    __shared__ int eds[4096];
    __shared__ int fh[1024];
    __shared__ int wsums[4];
    const int b = blockIdx.x, tid = threadIdx.x;
    const int lane = tid & 63, w = tid >> 6;

    const int base = histoff[b * nblk];
    const int endb = histoff[(b + 1) * nblk];    // histoff[nbkt*nblk] = E sentinel
    int cnt = endb - base;
    if (cnt > 4096) cnt = 4096;                  // Poisson max ~2.3k; safety clamp

    #pragma unroll
    for (int i = 0; i < 4; ++i) fh[tid + i * 256] = 0;
    __syncthreads();

    for (int i = tid; i < cnt; i += 256) {
        int e = tmp[base + i];
        eds[i] = e;
        int fb = ((e >> 16) << 3) + ((e & 0xffff) >> shift);
        atomicAdd(&fh[fb], 1);
    }
    __syncthreads();

    // exclusive scan of fh[0..1024)
    int v0 = fh[tid * 4], v1 = fh[tid * 4 + 1], v2 = fh[tid * 4 + 2], v3 = fh[tid * 4 + 3];
    int s0 = v0, s1 = s0 + v1, s2 = s1 + v2, s3 = s2 + v3;
    int x = s3;
    #pragma unroll
    for (int off = 1; off < 64; off <<= 1) {
        int t = __shfl_up(x, off, 64);
        if (lane >= off) x += t;
    }
    if (lane == 63) wsums[w] = x;
    __syncthreads();
    int wbase = 0;
    #pragma unroll
    for (int k = 0; k < 4; ++k) if (k < w) wbase += wsums[k];
    const int tb = wbase + x - s3;

    // write scanned offsets back to fh (as scatter cursors) + global offsets
    int o0 = tb, o1 = tb + s0, o2 = tb + s1, o3 = tb + s2;
    fh[tid * 4]     = o0;
    fh[tid * 4 + 1] = o1;
    fh[tid * 4 + 2] = o2;
    fh[tid * 4 + 3] = o3;
    int g = b * 1024 + tid * 4;
    if (g < nb)     offsets[g]     = base + o0;
    if (g + 1 < nb) offsets[g + 1] = base + o1;
    if (g + 2 < nb) offsets[g + 2] = base + o2;
    if (g + 3 < nb) offsets[g + 3] = base + o3;
    __syncthreads();

    // scatter via LDS cursor bump
    for (int i = tid; i < cnt; i += 256) {
        int e = eds[i];
        int fb = ((e >> 16) << 3) + ((e & 0xffff) >> shift);
        int p = atomicAdd(&fh[fb], 1);
        csr_src[base + p] = e & 0xffff;
    }
    if (b == 0 && tid == 0) offsets[nb] = nedges;
}

// standalone GEMM (layer 2, fp16 input, fp16 W 2-term)
__global__ __launch_bounds__(256) void gemm_mfma_f16_kernel(
    const _Float16* __restrict__ X, const h16x8* __restrict__ wf,
    const h16x8* __restrict__ wext, _Float16* __restrict__ featH,
    float* __restrict__ el, float* __restrict__ er, int nnodes, int ntiles)
{
    __shared__ h16x8 lw[2048];
    gemm_body_f16(X, wf, wext, featH, el, er, nnodes,
                  blockIdx.x, ntiles, gridDim.x, lw);
}

// ---------------------------------------------------------------------------
// Two-dispatch scan (proven), over the coarse count matrix.
// ---------------------------------------------------------------------------
__global__ __launch_bounds__(256) void scan1_kernel(
    const int* __restrict__ counts, int* __restrict__ offsets,
    int* __restrict__ bsums, int n)
{
    __shared__ int wsums[4];
    const int tid = threadIdx.x, lane = tid & 63, w = tid >> 6;
    const int i = blockIdx.x * 1024 + tid * 4;

    int4 v = make_int4(0, 0, 0, 0);
    if (i + 3 < n) v = *(const int4*)&counts[i];
    else {
        if (i < n)     v.x = counts[i];
        if (i + 1 < n) v.y = counts[i + 1];
        if (i + 2 < n) v.z = counts[i + 2];
    }
    int s0 = v.x, s1 = s0 + v.y, s2 = s1 + v.z, s3 = s2 + v.w;

    int x = s3;
    #pragma unroll
    for (int off = 1; off < 64; off <<= 1) {
        int t = __shfl_up(x, off, 64);
        if (lane >= off) x += t;
    }
    if (lane == 63) wsums[w] = x;
    __syncthreads();
    int wbase = 0;
    #pragma unroll
    for (int k = 0; k < 4; ++k) if (k < w) wbase += wsums[k];

    int tbase = wbase + x - s3;
    if (i < n)     offsets[i]     = tbase;
    if (i + 1 < n) offsets[i + 1] = tbase + s0;
    if (i + 2 < n) offsets[i + 2] = tbase + s1;
    if (i + 3 < n) offsets[i + 3] = tbase + s2;
    if (tid == 255) bsums[blockIdx.x] = wbase + x;
}

__global__ __launch_bounds__(256) void scan23_kernel(
    int* __restrict__ offsets, const int* __restrict__ bsums, int n, int nedges)
{
    __shared__ int sbase;
    const int tid = threadIdx.x, b = blockIdx.x;
    if (tid < 64) {
        int s = 0;
        for (int i = tid; i < b; i += 64) s += bsums[i];
        #pragma unroll
        for (int off = 1; off < 64; off <<= 1) s += __shfl_xor(s, off, 64);
        if (tid == 0) sbase = s;
    }
    __syncthreads();
    const int base = sbase;
    const int i = b * 1024 + tid * 4;
    #pragma unroll
    for (int k = 0; k < 4; ++k)
        if (i + k < n) offsets[i + k] += base;
    if (b == 0 && tid == 0) offsets[n] = nedges;
}

// ---------------------------------------------------------------------------
// Gather aggregation: one wave per node. csr indices prefetched 4 iters
// ahead (sc/sd/se queue) so the el/featH loads never wait on a same-iter
// csr load; feat/el prefetched 2 iters ahead.
// ---------------------------------------------------------------------------
template <bool MEAN>
__global__ __launch_bounds__(256) void aggregate_kernel(
    const _Float16* __restrict__ featH, const float* __restrict__ el,
    const float* __restrict__ er, const int* __restrict__ offsets,
    const int* __restrict__ csr_src, void* __restrict__ outp, int nnodes)
{
    const int n = (blockIdx.x * 256 + threadIdx.x) >> 6;   // wave-uniform
    if (n >= nnodes) return;
    const int lane = threadIdx.x & 63;
    const int g = lane >> 4, u = lane & 15, h = u >> 2;
    const int beg = offsets[n * NBUCK], end = offsets[n * NBUCK + NBUCK];
    const float ern = er[n * HEADS + h];
    const int iters = (end - beg + 3) >> 2;

    float a[8];
    #pragma unroll
    for (int p = 0; p < 8; ++p) a[p] = 0.f;
    float sw = 0.f;

    const h16x8* __restrict__ frow = (const h16x8*)featH;

    int ja = beg + g;
    int jb = ja + 4;
    int jc = ja + 8;
    int jd = ja + 12;
    bool va = ja < end, vb = jb < end;
    int sa = va ? csr_src[ja] : 0;
    int sb = vb ? csr_src[jb] : 0;
    int sc = jc < end ? csr_src[jc] : 0;
    int sd = jd < end ? csr_src[jd] : 0;
    float qa = el[sa * HEADS + h];
    float qb = el[sb * HEADS + h];
    h16x8 fa = frow[(size_t)sa * 16 + u];
    h16x8 fb = frow[(size_t)sb * 16 + u];

    for (int it = 0; it < iters; ++it) {
        int je = jd + 4;
        int se = je < end ? csr_src[je] : 0;
        float qc = el[sc * HEADS + h];          // sc arrived 2 iters ago
        h16x8 fc = frow[(size_t)sc * 16 + u];

        float e = qa + ern;
        e = e > 0.f ? e : NEG * e;
        float w2 = va ? __expf(e) : 0.f;
        #pragma unroll
        for (int p = 0; p < 8; ++p) a[p] += w2 * (float)fa[p];
        sw += w2;

        ja = jb; va = vb;
        jb = jc; vb = jb < end;
        qa = qb; fa = fb;
        qb = qc; fb = fc;
        sc = sd; sd = se;
        jc = jd; jd = je;
    }

    #pragma unroll
    for (int p = 0; p < 8; ++p) {
        a[p] += __shfl_xor(a[p], 16, 64);
        a[p] += __shfl_xor(a[p], 32, 64);
    }
    sw += __shfl_xor(sw, 16, 64);
    sw += __shfl_xor(sw, 32, 64);

    float inv = sw > 0.f ? 1.f / sw : 0.f;
    float r[8];
    #pragma unroll
    for (int p = 0; p < 8; ++p) {
        float t = a[p] * inv;
        r[p] = t > 0.f ? t : __expf(t) - 1.f;   // ELU
    }

    if (!MEAN) {
        if (g == 0) {
            h16x8 o;
            #pragma unroll
            for (int p = 0; p < 8; ++p) o[p] = (_Float16)r[p];
            ((h16x8*)outp)[(size_t)n * 16 + u] = o;
        }
    } else {
        #pragma unroll
        for (int p = 0; p < 8; ++p) {
            r[p] += __shfl_xor(r[p], 4, 64);
            r[p] += __shfl_xor(r[p], 8, 64);
        }
        if (g == 0 && u < 4) {
            float* out = (float*)outp;
            float4* o4 = (float4*)(out + (size_t)n * 32 + u * 8);
            o4[0] = make_float4(0.25f * r[0], 0.25f * r[1], 0.25f * r[2], 0.25f * r[3]);
            o4[1] = make_float4(0.25f * r[4], 0.25f * r[5], 0.25f * r[6], 0.25f * r[7]);
        }
    }
}

// ---------------------------------------------------------------------------
extern "C" void kernel_launch(void* const* d_in, const int* in_sizes, int n_in,
                              void* d_out, int out_size, void* d_ws, size_t ws_size,
                              hipStream_t stream)
{
    const float* x   = (const float*)d_in[0];
    const int*   src = (const int*)d_in[1];
    const int*   dst = (const int*)d_in[2];
    const float* W1  = (const float*)d_in[3];
    const float* al1 = (const float*)d_in[4];
    const float* ar1 = (const float*)d_in[5];
    const float* W2  = (const float*)d_in[6];
    const float* al2 = (const float*)d_in[7];
    const float* ar2 = (const float*)d_in[8];

    const int N = in_sizes[0] / FDIM;
    const int E = in_sizes[1];
    const int NB = N * NBUCK;

    int shift = 0;
    while (((N - 1) >> shift) > (NBUCK - 1)) ++shift;

    const int NBKT  = (N + CMASK) >> CSHIFT;       // coarse buckets (391)
    const int NBLK1 = (E + 2047) >> 11;            // edge blocks (391)
    const int n1    = NBKT * NBLK1;                // count-matrix entries

    _Float16* h1 = (_Float16*)d_ws;
    _Float16* featH = h1 + (size_t)N * FDIM;
    float* el = (float*)(featH + (size_t)N * FDIM);
    float* er = el + (size_t)N * HEADS;
    uintptr_t tp = ((uintptr_t)(er + (size_t)N * HEADS) + 15) & ~(uintptr_t)15;
    int* tmp     = (int*)tp;                       // E (packed edges)
    int* histmat = tmp + E;                        // n1
    int* histoff = histmat + n1;                   // n1 + 1
    int* offsets = histoff + (n1 + 1);             // NB + 1
    int* csr_src = offsets + (NB + 1);             // E
    int* bsums   = csr_src + E;                    // 512
    uintptr_t wp = ((uintptr_t)(bsums + 512) + 63) & ~(uintptr_t)63;
    __bf16* wf1     = (__bf16*)wp;                 // 32768 bf16
    __bf16* wext1   = wf1 + 32768;                 // 4096 bf16
    _Float16* wf2   = (_Float16*)(wext1 + 4096);   // 32768 fp16
    _Float16* wext2 = wf2 + 32768;                 // 4096 fp16

    const int ntiles = (N + 63) / 64;
    const int halfT  = (ntiles + 1) / 2;
    const int gA = halfT < 256 ? halfT : 256;
    const int gB = (ntiles - halfT) < 256 ? (ntiles - halfT) : 256;
    const int agg_grid  = (N + 3) / 4;             // 1 wave/node, 4 waves/block
    const int nscan     = (n1 + 1023) / 1024;      // <= 512 (bsums bound)
    const int g2 = ntiles < 512 ? ntiles : 512;

    // ---- W preprocessing ----
    prep_kernel<<<258, 256, 0, stream>>>(
        W1, al1, ar1, W2, al2, ar2, wf1, wext1, wf2, wext2);

    // ---- [gemm1 first half ∥ coarse LDS hist] ----
    fused_gemm_chist<<<gA + NBLK1, 256, 0, stream>>>(
        x, (const bf16x8*)wf1, (const bf16x8*)wext1, featH, el, er, N,
        0, halfT, gA, dst, histmat, E, NBLK1, NBKT);

    // ---- scan of (bucket, block) count matrix ----
    scan1_kernel<<<nscan, 256, 0, stream>>>(histmat, histoff, bsums, n1);
    scan23_kernel<<<nscan, 256, 0, stream>>>(histoff, bsums, n1, E);

    // ---- [gemm1 second half ∥ coarse scatter (LDS ranks, packed)] ----
    fused_gemm_cscatter<<<gB + NBLK1, 256, 0, stream>>>(
        x, (const bf16x8*)wf1, (const bf16x8*)wext1, featH, el, er, N,
        halfT, ntiles, gB, src, dst, histoff, tmp, E, NBLK1, NBKT);

    // ---- fine sort within buckets (LDS-only) ----
    fine_sort_kernel<<<NBKT, 256, 0, stream>>>(
        tmp, histoff, csr_src, offsets, NBLK1, NBKT, NB, E, shift);

    // ---- layer 1 aggregate ----
    aggregate_kernel<false><<<agg_grid, 256, 0, stream>>>(
        featH, el, er, offsets, csr_src, (void*)h1, N);

    // ---- layer 2 ----
    gemm_mfma_f16_kernel<<<g2, 256, 0, stream>>>(
        h1, (const h16x8*)wf2, (const h16x8*)wext2, featH, el, er, N, ntiles);
    aggregate_kernel<true><<<agg_grid, 256, 0, stream>>>(
        featH, el, er, offsets, csr_src, d_out, N);
}